// Round 4
// baseline (1557.960 us; speedup 1.0000x reference)
//
#include <hip/hip_runtime.h>
#include <math.h>

#define NB 96
#define NA 48
#define NF 128
#define NK 64
#define NL 6
#define NN (NB*NA)     // 4608 nodes
#define F3 (3*NF)      // 384
#define CUTF 5.0f
#define GAMMA_F ((float)(1.0 / (0.006103515625 + 1e-9)))
#define PI_F 3.14159265358979323846f

typedef __attribute__((ext_vector_type(8))) short short8;
typedef __attribute__((ext_vector_type(4))) float floatx4;

__device__ __forceinline__ float silu_f(float x) { return x / (1.0f + expf(-x)); }

__device__ __forceinline__ short f2bf(float x) {
    unsigned u = __builtin_bit_cast(unsigned, x);
    unsigned r = (u + 0x7fffu + ((u >> 16) & 1u)) >> 16;   // RNE
    return (short)r;
}
__device__ __forceinline__ float bf2f(short h) {
    unsigned u = ((unsigned)(unsigned short)h) << 16;
    return __builtin_bit_cast(float, u);
}
__device__ __forceinline__ floatx4 mfma2(short8 a, short8 bh, short8 bl, floatx4 c) {
    c = __builtin_amdgcn_mfma_f32_16x16x32_bf16(a, bh, c, 0, 0, 0);
    c = __builtin_amdgcn_mfma_f32_16x16x32_bf16(a, bl, c, 0, 0, 0);
    return c;
}
__device__ __forceinline__ floatx4 mfma3(short8 ah, short8 al, short8 bh, short8 bl, floatx4 c) {
    c = __builtin_amdgcn_mfma_f32_16x16x32_bf16(ah, bh, c, 0, 0, 0);
    c = __builtin_amdgcn_mfma_f32_16x16x32_bf16(al, bh, c, 0, 0, 0);
    c = __builtin_amdgcn_mfma_f32_16x16x32_bf16(ah, bl, c, 0, 0, 0);
    return c;
}

// ---------------- fused prep: 7 weight matrices -> transposed bf16 hi/lo [N][K] ----------------
__global__ void prep_kernel(const float* __restrict__ msg_w1, const float* __restrict__ msg_w2,
                            const float* __restrict__ rbf_w, const float* __restrict__ upd_U,
                            const float* __restrict__ upd_V, const float* __restrict__ upd_w1,
                            const float* __restrict__ upd_w2,
                            short* w1T_h, short* w1T_l, short* w2T_h, short* w2T_l,
                            short* rbfT_h, short* rbfT_l, short* UT_h, short* UT_l,
                            short* VT_h, short* VT_l, short* u1T_h, short* u1T_l,
                            short* u2T_h, short* u2T_l) {
    int m = blockIdx.y;
    int l = blockIdx.x / 384;
    int n = blockIdx.x % 384;
    const float* src; short* dh; short* dl; int K, N;
    switch (m) {
      case 0: src = msg_w1; dh = w1T_h; dl = w1T_l; K = NF;   N = NF; break;
      case 1: src = msg_w2; dh = w2T_h; dl = w2T_l; K = NF;   N = F3; break;
      case 2: src = rbf_w;  dh = rbfT_h;dl = rbfT_l;K = NK;   N = F3; break;
      case 3: src = upd_U;  dh = UT_h;  dl = UT_l;  K = NF;   N = NF; break;
      case 4: src = upd_V;  dh = VT_h;  dl = VT_l;  K = NF;   N = NF; break;
      case 5: src = upd_w1; dh = u1T_h; dl = u1T_l; K = 2*NF; N = NF; break;
      default:src = upd_w2; dh = u2T_h; dl = u2T_l; K = NF;   N = F3; break;
    }
    if (n >= N) return;
    for (int k = threadIdx.x; k < K; k += 64) {
        float x = src[((size_t)l*K + k)*N + n];
        short h = f2bf(x);
        dh[((size_t)l*N + n)*K + k] = h;
        dl[((size_t)l*N + n)*K + k] = f2bf(x - bf2f(h));
    }
}

// ---------------- geometry (layer-invariant): tk bf16 [i][48][64], we [i][48], dir [c][i][48] ----------------
__global__ void __launch_bounds__(384) geom_kernel(const float* __restrict__ pos,
                                                   short* __restrict__ tkG,
                                                   float* __restrict__ weG,
                                                   float* __restrict__ dirG) {
    int i = blockIdx.x;
    int b = i / NA, il = i % NA;
    int t = threadIdx.x;
    __shared__ float px[NA], py[NA], pz[NA];
    if (t < NA) {
        px[t] = pos[(b*NA+t)*3 + 0];
        py[t] = pos[(b*NA+t)*3 + 1];
        pz[t] = pos[(b*NA+t)*3 + 2];
    }
    __syncthreads();
    int j = t >> 3;
    int klo = (t & 7) * 8;
    float dx = px[il] - px[j], dy = py[il] - py[j], dz = pz[il] - pz[j];
    float d2 = dx*dx + dy*dy + dz*dz;
    float dd = sqrtf((j == il) ? 1.0f : d2);     // matches where(eye,1,d2)
    bool valid = (j != il) && (dd < CUTF);
    float we = valid ? 0.5f*(cosf(PI_F * dd / CUTF) + 1.0f) : 0.0f;
    if ((t & 7) == 0) {
        weG[(size_t)i*NA + j] = we;
        float inv = 1.0f / dd;
        dirG[0*(size_t)NN*NA + i*NA + j] = dx*inv;
        dirG[1*(size_t)NN*NA + i*NA + j] = dy*inv;
        dirG[2*(size_t)NN*NA + i*NA + j] = dz*inv;
    }
    short8 h8;
    #pragma unroll
    for (int kk = 0; kk < 8; ++kk) {
        int k = klo + kk;
        float c = CUTF * (float)k / 63.0f;
        float df = dd - c;
        h8[kk] = f2bf(expf(-GAMMA_F * df * df) * we);
    }
    *(short8*)(tkG + (size_t)i*(NA*NK) + j*NK + klo) = h8;
}

// ---------------- init ----------------
__global__ void init_kernel(const float* __restrict__ emb, const int* __restrict__ node_atom,
                            float* __restrict__ s, float* __restrict__ v) {
    int n = blockIdx.x, f = threadIdx.x;
    int a = node_atom[n];
    s[n*NF + f] = emb[a*NF + f];
    v[n*F3 + f] = 0.f;
    v[n*F3 + NF + f] = 0.f;
    v[n*F3 + 2*NF + f] = 0.f;
}

// ---------------- phi MLP via MFMA x3: phi[n][384] = silu(s@w1+b1)@w2+b2 ----------------
// 16 nodes/block, 128 threads (2 waves)
__global__ void __launch_bounds__(128) phi_kernel(const float* __restrict__ sIn,
                                                  const short* __restrict__ w1T_h, const short* __restrict__ w1T_l,
                                                  const float* __restrict__ b1,
                                                  const short* __restrict__ w2T_h, const short* __restrict__ w2T_l,
                                                  const float* __restrict__ b2,
                                                  float* __restrict__ phi) {
    __shared__ short sH[16*NF], sL[16*NF];
    __shared__ short hH[16*NF], hL[16*NF];
    int t = threadIdx.x;
    int w = t >> 6, lane = t & 63, quad = lane >> 4, col = lane & 15;
    int n0 = blockIdx.x * 16;
    for (int e = t; e < 16*NF; e += 128) {
        int n = e >> 7, f = e & 127;
        float x = sIn[(size_t)(n0+n)*NF + f];
        short h = f2bf(x);
        int ad = n*NF + (((f >> 3) ^ (n & 7)) << 3) + (f & 7);
        sH[ad] = h; sL[ad] = f2bf(x - bf2f(h));
    }
    __syncthreads();
    // GEMM1: wave w covers h-features [64w, 64w+64)
    #pragma unroll
    for (int nt = 0; nt < 4; ++nt) {
        int fh = w*64 + nt*16 + col;
        floatx4 acc = (floatx4){0.f,0.f,0.f,0.f};
        #pragma unroll
        for (int ks = 0; ks < 4; ++ks) {
            int ad = col*NF + (((ks*4 + quad) ^ (col & 7)) << 3);
            size_t off = (size_t)fh*NF + ks*32 + quad*8;
            acc = mfma3(*(short8*)&sH[ad], *(short8*)&sL[ad],
                        *(const short8*)(w1T_h + off), *(const short8*)(w1T_l + off), acc);
        }
        float bias = b1[fh];
        #pragma unroll
        for (int r = 0; r < 4; ++r) {
            int n = quad*4 + r;
            float hv = silu_f(acc[r] + bias);
            short h = f2bf(hv);
            int ad = n*NF + (((fh >> 3) ^ (n & 7)) << 3) + (fh & 7);
            hH[ad] = h; hL[ad] = f2bf(hv - bf2f(h));
        }
    }
    __syncthreads();
    // GEMM2: wave w covers t in [192w, 192w+192)
    #pragma unroll
    for (int nt = 0; nt < 12; ++nt) {
        int tt = w*192 + nt*16 + col;
        floatx4 acc = (floatx4){0.f,0.f,0.f,0.f};
        #pragma unroll
        for (int ks = 0; ks < 4; ++ks) {
            int ad = col*NF + (((ks*4 + quad) ^ (col & 7)) << 3);
            size_t off = (size_t)tt*NF + ks*32 + quad*8;
            acc = mfma3(*(short8*)&hH[ad], *(short8*)&hL[ad],
                        *(const short8*)(w2T_h + off), *(const short8*)(w2T_l + off), acc);
        }
        float bias = b2[tt];
        #pragma unroll
        for (int r = 0; r < 4; ++r)
            phi[(size_t)(n0 + quad*4 + r)*F3 + tt] = acc[r] + bias;
    }
}

// ---------------- message: block = (graph, 8-atom tile), 768 thr = 12 waves ----------------
// waves 0-3: ds (f=32*sub..), 4-7: dvv, 8-11: dvs. tk staged in swizzled LDS (shared by all waves).
__global__ void __launch_bounds__(768, 1) message_kernel(
        const float* __restrict__ sIn, const float* __restrict__ vIn,
        const float* __restrict__ phi, const short* __restrict__ tkG,
        const short* __restrict__ rbfT_h, const short* __restrict__ rbfT_l,
        const float* __restrict__ rbf_b_l,
        const float* __restrict__ weG, const float* __restrict__ dirG,
        float* __restrict__ sOut, float* __restrict__ vOut) {
    __shared__ short tkL[8*48*64];   // 48 KB, XOR-swizzled chunks of 8 shorts
    __shared__ float red[2*3*NF];    // dvs -> dvv handoff, 2 atoms per chunk
    int graph = blockIdx.x / 6, itile = blockIdx.x % 6;
    int i0 = graph*48 + itile*8;
    int jbase = graph*48;
    int t = threadIdx.x;
    int w = t >> 6, lane = t & 63, quad = lane >> 4, col = lane & 15;
    int g = w >> 2, sub = w & 3;
    // stage tk (8 atoms x 48 j x 64 k bf16)
    for (int e = t; e < 3072; e += 768) {
        int ii = e / 384, rem = e % 384;
        int j = rem >> 3, ch = rem & 7;
        short8 val = *(const short8*)(tkG + ((size_t)(i0+ii)*NA + j)*NK + ch*8);
        *(short8*)&tkL[((ii*NA + j) << 6) + ((ch ^ (j & 7)) << 3)] = val;
    }
    int fC = sub*32;
    int Tb = g*128 + fC;
    short8 Bh[2][2], Bl[2][2];
    float rb[2];
    #pragma unroll
    for (int nt = 0; nt < 2; ++nt) {
        int tt = Tb + nt*16 + col;
        rb[nt] = rbf_b_l[tt];
        #pragma unroll
        for (int ks = 0; ks < 2; ++ks) {
            size_t off = (size_t)tt*NK + ks*32 + quad*8;
            Bh[nt][ks] = *(const short8*)(rbfT_h + off);
            Bl[nt][ks] = *(const short8*)(rbfT_l + off);
        }
    }
    __syncthreads();
    for (int ic = 0; ic < 4; ++ic) {
        floatx4 C[2][3][2];
        #pragma unroll
        for (int ii = 0; ii < 2; ++ii)
            #pragma unroll
            for (int mt = 0; mt < 3; ++mt)
                #pragma unroll
                for (int nt = 0; nt < 2; ++nt) C[ii][mt][nt] = (floatx4){0.f,0.f,0.f,0.f};
        #pragma unroll
        for (int ii = 0; ii < 2; ++ii) {
            int il = ic*2 + ii;
            #pragma unroll
            for (int mt = 0; mt < 3; ++mt) {
                int j = mt*16 + col;
                #pragma unroll
                for (int ks = 0; ks < 2; ++ks) {
                    short8 a = *(short8*)&tkL[((il*NA + j) << 6) + (((ks*4 + quad) ^ (j & 7)) << 3)];
                    #pragma unroll
                    for (int nt = 0; nt < 2; ++nt)
                        C[ii][mt][nt] = mfma2(a, Bh[nt][ks], Bl[nt][ks], C[ii][mt][nt]);
                }
            }
        }
        float a0[2][2], a1[2][2], a2[2][2];   // [ii][nt] per-component accumulators (dvv/dvs)
        float accS[2][2];
        #pragma unroll
        for (int ii = 0; ii < 2; ++ii)
            #pragma unroll
            for (int nt = 0; nt < 2; ++nt) { a0[ii][nt]=0.f; a1[ii][nt]=0.f; a2[ii][nt]=0.f; accS[ii][nt]=0.f; }
        #pragma unroll
        for (int ii = 0; ii < 2; ++ii) {
            int i = i0 + ic*2 + ii;
            #pragma unroll
            for (int mt = 0; mt < 3; ++mt) {
                int jq = mt*16 + quad*4;
                floatx4 we4 = *(const floatx4*)(weG + (size_t)i*NA + jq);
                if (g == 0) {
                    #pragma unroll
                    for (int nt = 0; nt < 2; ++nt) {
                        int tt = fC + nt*16 + col;
                        #pragma unroll
                        for (int r = 0; r < 4; ++r) {
                            float Wf = fmaf(rb[nt], we4[r], C[ii][mt][nt][r]);
                            float ph = phi[(size_t)(jbase + jq + r)*F3 + tt];
                            accS[ii][nt] = fmaf(ph, Wf, accS[ii][nt]);
                        }
                    }
                } else if (g == 1) {
                    #pragma unroll
                    for (int nt = 0; nt < 2; ++nt) {
                        int f = fC + nt*16 + col;
                        #pragma unroll
                        for (int r = 0; r < 4; ++r) {
                            float Wf = fmaf(rb[nt], we4[r], C[ii][mt][nt][r]);
                            const float* vp = vIn + (size_t)(jbase + jq + r)*F3 + f;
                            float ph = phi[(size_t)(jbase + jq + r)*F3 + NF + f];
                            float x = ph * Wf;
                            a0[ii][nt] = fmaf(x, vp[0],    a0[ii][nt]);
                            a1[ii][nt] = fmaf(x, vp[NF],   a1[ii][nt]);
                            a2[ii][nt] = fmaf(x, vp[2*NF], a2[ii][nt]);
                        }
                    }
                } else {
                    floatx4 d0 = *(const floatx4*)(dirG + 0*(size_t)NN*NA + (size_t)i*NA + jq);
                    floatx4 d1 = *(const floatx4*)(dirG + 1*(size_t)NN*NA + (size_t)i*NA + jq);
                    floatx4 d2v = *(const floatx4*)(dirG + 2*(size_t)NN*NA + (size_t)i*NA + jq);
                    #pragma unroll
                    for (int nt = 0; nt < 2; ++nt) {
                        int f = fC + nt*16 + col;
                        #pragma unroll
                        for (int r = 0; r < 4; ++r) {
                            float Wf = fmaf(rb[nt], we4[r], C[ii][mt][nt][r]);
                            float ph = phi[(size_t)(jbase + jq + r)*F3 + 2*NF + f];
                            float x = ph * Wf;
                            a0[ii][nt] = fmaf(x, d0[r],  a0[ii][nt]);
                            a1[ii][nt] = fmaf(x, d1[r],  a1[ii][nt]);
                            a2[ii][nt] = fmaf(x, d2v[r], a2[ii][nt]);
                        }
                    }
                }
            }
        }
        // reduce over quads and hand off
        #pragma unroll
        for (int ii = 0; ii < 2; ++ii) {
            #pragma unroll
            for (int nt = 0; nt < 2; ++nt) {
                if (g == 0) {
                    accS[ii][nt] += __shfl_xor(accS[ii][nt], 16, 64);
                    accS[ii][nt] += __shfl_xor(accS[ii][nt], 32, 64);
                } else {
                    a0[ii][nt] += __shfl_xor(a0[ii][nt], 16, 64); a0[ii][nt] += __shfl_xor(a0[ii][nt], 32, 64);
                    a1[ii][nt] += __shfl_xor(a1[ii][nt], 16, 64); a1[ii][nt] += __shfl_xor(a1[ii][nt], 32, 64);
                    a2[ii][nt] += __shfl_xor(a2[ii][nt], 16, 64); a2[ii][nt] += __shfl_xor(a2[ii][nt], 32, 64);
                }
            }
        }
        if (g == 2 && quad == 0) {
            #pragma unroll
            for (int ii = 0; ii < 2; ++ii)
                #pragma unroll
                for (int nt = 0; nt < 2; ++nt) {
                    int f = fC + nt*16 + col;
                    red[ii*F3 + 0*NF + f] = a0[ii][nt];
                    red[ii*F3 + 1*NF + f] = a1[ii][nt];
                    red[ii*F3 + 2*NF + f] = a2[ii][nt];
                }
        }
        if (g == 0 && quad == 0) {
            #pragma unroll
            for (int ii = 0; ii < 2; ++ii) {
                int i = i0 + ic*2 + ii;
                #pragma unroll
                for (int nt = 0; nt < 2; ++nt) {
                    int f = fC + nt*16 + col;
                    sOut[(size_t)i*NF + f] = sIn[(size_t)i*NF + f] + accS[ii][nt];
                }
            }
        }
        __syncthreads();
        if (g == 1 && quad == 0) {
            #pragma unroll
            for (int ii = 0; ii < 2; ++ii) {
                int i = i0 + ic*2 + ii;
                #pragma unroll
                for (int nt = 0; nt < 2; ++nt) {
                    int f = fC + nt*16 + col;
                    #pragma unroll
                    for (int c = 0; c < 3; ++c) {
                        size_t o = (size_t)i*F3 + c*NF + f;
                        float dvs = red[ii*F3 + c*NF + f];
                        float acc = (c == 0) ? a0[ii][nt] : ((c == 1) ? a1[ii][nt] : a2[ii][nt]);
                        vOut[o] = vIn[o] + dvs + acc;
                    }
                }
            }
        }
        __syncthreads();
    }
}

// ---------------- update via MFMA x3: 16 nodes/block, 256 thr (4 waves) ----------------
__global__ void __launch_bounds__(256, 2) update_kernel(
        const short* __restrict__ UT_h, const short* __restrict__ UT_l,
        const short* __restrict__ VT_h, const short* __restrict__ VT_l,
        const short* __restrict__ u1T_h, const short* __restrict__ u1T_l,
        const float* __restrict__ b1,
        const short* __restrict__ u2T_h, const short* __restrict__ u2T_l,
        const float* __restrict__ b2,
        float* __restrict__ s, float* __restrict__ v) {
    __shared__ short A1h[48*NF], A1l[48*NF];    // v rows = c*16+n, swizzled
    __shared__ short A2h[16*256], A2l[16*256];  // [s ; Vn]
    __shared__ short hH[16*NF], hL[16*NF];
    __shared__ float sF[16*132];
    int t = threadIdx.x;
    int w = t >> 6, lane = t & 63, quad = lane >> 4, col = lane & 15;
    int n0 = blockIdx.x * 16;
    int fC = w * 32;
    for (int e = t; e < 16*F3; e += 256) {
        int n = e / F3, cf = e % F3;
        int c = cf >> 7, f = cf & 127;
        float x = v[(size_t)(n0+n)*F3 + cf];
        int row = c*16 + n;
        short h = f2bf(x);
        int ad = row*NF + (((f >> 3) ^ (row & 7)) << 3) + (f & 7);
        A1h[ad] = h; A1l[ad] = f2bf(x - bf2f(h));
    }
    for (int e = t; e < 16*NF; e += 256) {
        int n = e >> 7, f = e & 127;
        float x = s[(size_t)(n0+n)*NF + f];
        sF[n*132 + f] = x;
        short h = f2bf(x);
        int ad = n*256 + (((f >> 3) ^ (n & 7)) << 3) + (f & 7);
        A2h[ad] = h; A2l[ad] = f2bf(x - bf2f(h));
    }
    __syncthreads();
    // U/V projections: rows c*16+n, wave covers f-chunk [32w, 32w+32)
    floatx4 Uacc[3][2], Vacc[3][2];
    #pragma unroll
    for (int mt = 0; mt < 3; ++mt)
        #pragma unroll
        for (int nt = 0; nt < 2; ++nt) { Uacc[mt][nt] = (floatx4){0.f,0.f,0.f,0.f}; Vacc[mt][nt] = (floatx4){0.f,0.f,0.f,0.f}; }
    for (int ks = 0; ks < 4; ++ks) {
        short8 BUh[2], BUl[2], BVh[2], BVl[2];
        #pragma unroll
        for (int nt = 0; nt < 2; ++nt) {
            size_t off = (size_t)(fC + nt*16 + col)*NF + ks*32 + quad*8;
            BUh[nt] = *(const short8*)(UT_h + off); BUl[nt] = *(const short8*)(UT_l + off);
            BVh[nt] = *(const short8*)(VT_h + off); BVl[nt] = *(const short8*)(VT_l + off);
        }
        #pragma unroll
        for (int mt = 0; mt < 3; ++mt) {
            int row = mt*16 + col;
            int ad = row*NF + (((ks*4 + quad) ^ (row & 7)) << 3);
            short8 ah = *(short8*)&A1h[ad], al = *(short8*)&A1l[ad];
            #pragma unroll
            for (int nt = 0; nt < 2; ++nt) {
                Uacc[mt][nt] = mfma3(ah, al, BUh[nt], BUl[nt], Uacc[mt][nt]);
                Vacc[mt][nt] = mfma3(ah, al, BVh[nt], BVl[nt], Vacc[mt][nt]);
            }
        }
    }
    // Vn -> A2 columns [128, 256)
    #pragma unroll
    for (int nt = 0; nt < 2; ++nt) {
        int f = fC + nt*16 + col;
        #pragma unroll
        for (int r = 0; r < 4; ++r) {
            int n = quad*4 + r;
            float v0 = Vacc[0][nt][r], v1 = Vacc[1][nt][r], v2 = Vacc[2][nt][r];
            float vn = sqrtf(v0*v0 + v1*v1 + v2*v2 + 1e-8f);
            short h = f2bf(vn);
            int ad = n*256 + ((((128 + f) >> 3) ^ (n & 7)) << 3) + (f & 7);
            A2h[ad] = h; A2l[ad] = f2bf(vn - bf2f(h));
        }
    }
    __syncthreads();
    // MLP1: [16][256] @ [256][128] -> h
    {
        floatx4 H[2];
        #pragma unroll
        for (int nt = 0; nt < 2; ++nt) H[nt] = (floatx4){0.f,0.f,0.f,0.f};
        for (int ks = 0; ks < 8; ++ks) {
            int ad = col*256 + (((ks*4 + quad) ^ (col & 7)) << 3);
            short8 ah = *(short8*)&A2h[ad], al = *(short8*)&A2l[ad];
            #pragma unroll
            for (int nt = 0; nt < 2; ++nt) {
                size_t off = (size_t)(fC + nt*16 + col)*(2*NF) + ks*32 + quad*8;
                H[nt] = mfma3(ah, al, *(const short8*)(u1T_h + off), *(const short8*)(u1T_l + off), H[nt]);
            }
        }
        #pragma unroll
        for (int nt = 0; nt < 2; ++nt) {
            int f = fC + nt*16 + col;
            float bias = b1[f];
            #pragma unroll
            for (int r = 0; r < 4; ++r) {
                int n = quad*4 + r;
                float hv = silu_f(H[nt][r] + bias);
                short h = f2bf(hv);
                int ad = n*NF + (((f >> 3) ^ (n & 7)) << 3) + (f & 7);
                hH[ad] = h; hL[ad] = f2bf(hv - bf2f(h));
            }
        }
    }
    __syncthreads();
    // MLP2: [16][128] @ [128][384]; wave computes its f-chunk for all 3 output groups
    floatx4 O[3][2];
    #pragma unroll
    for (int gg = 0; gg < 3; ++gg)
        #pragma unroll
        for (int nt = 0; nt < 2; ++nt) O[gg][nt] = (floatx4){0.f,0.f,0.f,0.f};
    for (int ks = 0; ks < 4; ++ks) {
        int ad = col*NF + (((ks*4 + quad) ^ (col & 7)) << 3);
        short8 ah = *(short8*)&hH[ad], al = *(short8*)&hL[ad];
        #pragma unroll
        for (int gg = 0; gg < 3; ++gg)
            #pragma unroll
            for (int nt = 0; nt < 2; ++nt) {
                size_t off = (size_t)(gg*NF + fC + nt*16 + col)*NF + ks*32 + quad*8;
                O[gg][nt] = mfma3(ah, al, *(const short8*)(u2T_h + off), *(const short8*)(u2T_l + off), O[gg][nt]);
            }
    }
    #pragma unroll
    for (int nt = 0; nt < 2; ++nt) {
        int f = fC + nt*16 + col;
        float bavv = b2[f], basv = b2[NF + f], bass = b2[2*NF + f];
        #pragma unroll
        for (int r = 0; r < 4; ++r) {
            int n = quad*4 + r;
            float avv = O[0][nt][r] + bavv;
            float asv = O[1][nt][r] + basv;
            float ass = O[2][nt][r] + bass;
            float dot = Uacc[0][nt][r]*Vacc[0][nt][r] + Uacc[1][nt][r]*Vacc[1][nt][r]
                      + Uacc[2][nt][r]*Vacc[2][nt][r];
            s[(size_t)(n0+n)*NF + f] = sF[n*132 + f] + asv*dot + ass;
            #pragma unroll
            for (int c = 0; c < 3; ++c) {
                int row = c*16 + n;
                int ad = row*NF + (((f >> 3) ^ (row & 7)) << 3) + (f & 7);
                float vold = bf2f(A1h[ad]) + bf2f(A1l[ad]);
                v[(size_t)(n0+n)*F3 + c*NF + f] = vold + avv*Uacc[c][nt][r];
            }
        }
    }
}

// ---------------- output head ----------------
__global__ void zero_out_kernel(float* __restrict__ out) {
    out[threadIdx.x] = 0.f;
}

__global__ void out_kernel(const float* __restrict__ s,
                           const float* __restrict__ w1, const float* __restrict__ b1,
                           const float* __restrict__ w2, const float* __restrict__ b2,
                           float* __restrict__ out) {
    int n = blockIdx.x;
    int f = threadIdx.x;
    __shared__ float sh[NF];
    __shared__ float r2[2];
    sh[f] = s[n*NF + f];
    __syncthreads();
    float acc = b1[f];
    for (int g = 0; g < NF; ++g) acc = fmaf(sh[g], w1[g*NF + f], acc);
    float p = silu_f(acc) * w2[f];
    #pragma unroll
    for (int off = 32; off > 0; off >>= 1) p += __shfl_down(p, off, 64);
    if ((f & 63) == 0) r2[f >> 6] = p;
    __syncthreads();
    if (f == 0) atomicAdd(&out[n / NA], r2[0] + r2[1] + b2[0]);
}

extern "C" void kernel_launch(void* const* d_in, const int* in_sizes, int n_in,
                              void* d_out, int out_size, void* d_ws, size_t ws_size,
                              hipStream_t stream) {
    (void)in_sizes; (void)n_in; (void)out_size; (void)ws_size;
    const float* pos      = (const float*)d_in[1];
    const int*   node_atom= (const int*)  d_in[3];
    const float* emb      = (const float*)d_in[4];
    const float* msg_w1   = (const float*)d_in[5];
    const float* msg_b1   = (const float*)d_in[6];
    const float* msg_w2   = (const float*)d_in[7];
    const float* msg_b2   = (const float*)d_in[8];
    const float* rbf_w    = (const float*)d_in[9];
    const float* rbf_b    = (const float*)d_in[10];
    const float* upd_U    = (const float*)d_in[11];
    const float* upd_V    = (const float*)d_in[12];
    const float* upd_w1   = (const float*)d_in[13];
    const float* upd_b1   = (const float*)d_in[14];
    const float* upd_w2   = (const float*)d_in[15];
    const float* upd_b2   = (const float*)d_in[16];
    const float* out_w1   = (const float*)d_in[17];
    const float* out_b1   = (const float*)d_in[18];
    const float* out_w2   = (const float*)d_in[19];
    const float* out_b2   = (const float*)d_in[20];
    float* out = (float*)d_out;

    float* ws   = (float*)d_ws;
    float* sA   = ws; ws += (size_t)NN*NF;
    float* sB   = ws; ws += (size_t)NN*NF;
    float* vA   = ws; ws += (size_t)NN*F3;
    float* vB   = ws; ws += (size_t)NN*F3;
    float* phi  = ws; ws += (size_t)NN*F3;
    float* weG  = ws; ws += (size_t)NN*NA;
    float* dirG = ws; ws += (size_t)3*NN*NA;
    short* sp    = (short*)ws;
    short* tkG   = sp; sp += (size_t)NN*NA*NK;
    short* w1T_h = sp; sp += (size_t)NL*NF*NF;
    short* w1T_l = sp; sp += (size_t)NL*NF*NF;
    short* w2T_h = sp; sp += (size_t)NL*F3*NF;
    short* w2T_l = sp; sp += (size_t)NL*F3*NF;
    short* rbfT_h= sp; sp += (size_t)NL*F3*NK;
    short* rbfT_l= sp; sp += (size_t)NL*F3*NK;
    short* UT_h  = sp; sp += (size_t)NL*NF*NF;
    short* UT_l  = sp; sp += (size_t)NL*NF*NF;
    short* VT_h  = sp; sp += (size_t)NL*NF*NF;
    short* VT_l  = sp; sp += (size_t)NL*NF*NF;
    short* u1T_h = sp; sp += (size_t)NL*NF*2*NF;
    short* u1T_l = sp; sp += (size_t)NL*NF*2*NF;
    short* u2T_h = sp; sp += (size_t)NL*F3*NF;
    short* u2T_l = sp; sp += (size_t)NL*F3*NF;

    prep_kernel<<<dim3(NL*384, 7), 64, 0, stream>>>(msg_w1, msg_w2, rbf_w, upd_U, upd_V, upd_w1, upd_w2,
                                                    w1T_h, w1T_l, w2T_h, w2T_l, rbfT_h, rbfT_l,
                                                    UT_h, UT_l, VT_h, VT_l, u1T_h, u1T_l, u2T_h, u2T_l);
    geom_kernel<<<NN, 384, 0, stream>>>(pos, tkG, weG, dirG);
    init_kernel<<<NN, NF, 0, stream>>>(emb, node_atom, sA, vA);

    float* sC = sA; float* vC = vA; float* sN = sB; float* vN = vB;
    for (int l = 0; l < NL; ++l) {
        phi_kernel<<<NN/16, 128, 0, stream>>>(sC, w1T_h + (size_t)l*NF*NF, w1T_l + (size_t)l*NF*NF,
                                              msg_b1 + (size_t)l*NF,
                                              w2T_h + (size_t)l*F3*NF, w2T_l + (size_t)l*F3*NF,
                                              msg_b2 + (size_t)l*F3, phi);
        message_kernel<<<NB*6, 768, 0, stream>>>(sC, vC, phi, tkG,
                                                 rbfT_h + (size_t)l*F3*NK, rbfT_l + (size_t)l*F3*NK,
                                                 rbf_b + (size_t)l*F3, weG, dirG, sN, vN);
        update_kernel<<<NN/16, 256, 0, stream>>>(UT_h + (size_t)l*NF*NF, UT_l + (size_t)l*NF*NF,
                                                 VT_h + (size_t)l*NF*NF, VT_l + (size_t)l*NF*NF,
                                                 u1T_h + (size_t)l*NF*2*NF, u1T_l + (size_t)l*NF*2*NF,
                                                 upd_b1 + (size_t)l*NF,
                                                 u2T_h + (size_t)l*F3*NF, u2T_l + (size_t)l*F3*NF,
                                                 upd_b2 + (size_t)l*F3, sN, vN);
        float* tp;
        tp = sC; sC = sN; sN = tp;
        tp = vC; vC = vN; vN = tp;
    }
    zero_out_kernel<<<1, NB, 0, stream>>>(out);
    out_kernel<<<NN, NF, 0, stream>>>(sC, out_w1, out_b1, out_w2, out_b2, out);
}

// Round 5
// 1456.945 us; speedup vs baseline: 1.0693x; 1.0693x over previous
//
#include <hip/hip_runtime.h>
#include <math.h>

#define NB 96
#define NA 48
#define NF 128
#define NK 64
#define NL 6
#define NN (NB*NA)     // 4608 nodes
#define F3 (3*NF)      // 384
#define CUTF 5.0f
#define GAMMA_F ((float)(1.0 / (0.006103515625 + 1e-9)))
#define PI_F 3.14159265358979323846f

typedef __attribute__((ext_vector_type(8))) short short8;
typedef __attribute__((ext_vector_type(4))) float floatx4;

__device__ __forceinline__ float silu_f(float x) { return x / (1.0f + expf(-x)); }

__device__ __forceinline__ short f2bf(float x) {
    unsigned u = __builtin_bit_cast(unsigned, x);
    unsigned r = (u + 0x7fffu + ((u >> 16) & 1u)) >> 16;   // RNE
    return (short)r;
}
__device__ __forceinline__ float bf2f(short h) {
    unsigned u = ((unsigned)(unsigned short)h) << 16;
    return __builtin_bit_cast(float, u);
}
__device__ __forceinline__ floatx4 mfma2(short8 a, short8 bh, short8 bl, floatx4 c) {
    c = __builtin_amdgcn_mfma_f32_16x16x32_bf16(a, bh, c, 0, 0, 0);
    c = __builtin_amdgcn_mfma_f32_16x16x32_bf16(a, bl, c, 0, 0, 0);
    return c;
}
__device__ __forceinline__ floatx4 mfma3(short8 ah, short8 al, short8 bh, short8 bl, floatx4 c) {
    c = __builtin_amdgcn_mfma_f32_16x16x32_bf16(ah, bh, c, 0, 0, 0);
    c = __builtin_amdgcn_mfma_f32_16x16x32_bf16(al, bh, c, 0, 0, 0);
    c = __builtin_amdgcn_mfma_f32_16x16x32_bf16(ah, bl, c, 0, 0, 0);
    return c;
}

// ---------------- fused prep: 7 weight matrices -> transposed bf16 hi/lo [N][K] ----------------
__global__ void prep_kernel(const float* __restrict__ msg_w1, const float* __restrict__ msg_w2,
                            const float* __restrict__ rbf_w, const float* __restrict__ upd_U,
                            const float* __restrict__ upd_V, const float* __restrict__ upd_w1,
                            const float* __restrict__ upd_w2,
                            short* w1T_h, short* w1T_l, short* w2T_h, short* w2T_l,
                            short* rbfT_h, short* rbfT_l, short* UT_h, short* UT_l,
                            short* VT_h, short* VT_l, short* u1T_h, short* u1T_l,
                            short* u2T_h, short* u2T_l) {
    int m = blockIdx.y;
    int l = blockIdx.x / 384;
    int n = blockIdx.x % 384;
    const float* src; short* dh; short* dl; int K, N;
    switch (m) {
      case 0: src = msg_w1; dh = w1T_h; dl = w1T_l; K = NF;   N = NF; break;
      case 1: src = msg_w2; dh = w2T_h; dl = w2T_l; K = NF;   N = F3; break;
      case 2: src = rbf_w;  dh = rbfT_h;dl = rbfT_l;K = NK;   N = F3; break;
      case 3: src = upd_U;  dh = UT_h;  dl = UT_l;  K = NF;   N = NF; break;
      case 4: src = upd_V;  dh = VT_h;  dl = VT_l;  K = NF;   N = NF; break;
      case 5: src = upd_w1; dh = u1T_h; dl = u1T_l; K = 2*NF; N = NF; break;
      default:src = upd_w2; dh = u2T_h; dl = u2T_l; K = NF;   N = F3; break;
    }
    if (n >= N) return;
    for (int k = threadIdx.x; k < K; k += 64) {
        float x = src[((size_t)l*K + k)*N + n];
        short h = f2bf(x);
        dh[((size_t)l*N + n)*K + k] = h;
        dl[((size_t)l*N + n)*K + k] = f2bf(x - bf2f(h));
    }
}

// ---------------- init ----------------
__global__ void init_kernel(const float* __restrict__ emb, const int* __restrict__ node_atom,
                            float* __restrict__ s, float* __restrict__ v) {
    int n = blockIdx.x, f = threadIdx.x;
    int a = node_atom[n];
    s[n*NF + f] = emb[a*NF + f];
    v[n*F3 + f] = 0.f;
    v[n*F3 + NF + f] = 0.f;
    v[n*F3 + 2*NF + f] = 0.f;
}

__global__ void zero_kernel(float* __restrict__ p) {
    p[(size_t)blockIdx.x * blockDim.x + threadIdx.x] = 0.f;
}

// ---------------- phi MLP via MFMA x3 -> TRANSPOSED phiT[t][node] ----------------
// 16 nodes/block, 128 threads (2 waves)
__global__ void __launch_bounds__(128) phi_kernel(const float* __restrict__ sIn,
                                                  const short* __restrict__ w1T_h, const short* __restrict__ w1T_l,
                                                  const float* __restrict__ b1,
                                                  const short* __restrict__ w2T_h, const short* __restrict__ w2T_l,
                                                  const float* __restrict__ b2,
                                                  float* __restrict__ phiT) {
    __shared__ short sH[16*NF], sL[16*NF];
    __shared__ short hH[16*NF], hL[16*NF];
    int t = threadIdx.x;
    int w = t >> 6, lane = t & 63, quad = lane >> 4, col = lane & 15;
    int n0 = blockIdx.x * 16;
    for (int e = t; e < 16*NF; e += 128) {
        int n = e >> 7, f = e & 127;
        float x = sIn[(size_t)(n0+n)*NF + f];
        short h = f2bf(x);
        int ad = n*NF + (((f >> 3) ^ (n & 7)) << 3) + (f & 7);
        sH[ad] = h; sL[ad] = f2bf(x - bf2f(h));
    }
    __syncthreads();
    #pragma unroll
    for (int nt = 0; nt < 4; ++nt) {
        int fh = w*64 + nt*16 + col;
        floatx4 acc = (floatx4){0.f,0.f,0.f,0.f};
        #pragma unroll
        for (int ks = 0; ks < 4; ++ks) {
            int ad = col*NF + (((ks*4 + quad) ^ (col & 7)) << 3);
            size_t off = (size_t)fh*NF + ks*32 + quad*8;
            acc = mfma3(*(short8*)&sH[ad], *(short8*)&sL[ad],
                        *(const short8*)(w1T_h + off), *(const short8*)(w1T_l + off), acc);
        }
        float bias = b1[fh];
        #pragma unroll
        for (int r = 0; r < 4; ++r) {
            int n = quad*4 + r;
            float hv = silu_f(acc[r] + bias);
            short h = f2bf(hv);
            int ad = n*NF + (((fh >> 3) ^ (n & 7)) << 3) + (fh & 7);
            hH[ad] = h; hL[ad] = f2bf(hv - bf2f(h));
        }
    }
    __syncthreads();
    #pragma unroll
    for (int nt = 0; nt < 12; ++nt) {
        int tt = w*192 + nt*16 + col;
        floatx4 acc = (floatx4){0.f,0.f,0.f,0.f};
        #pragma unroll
        for (int ks = 0; ks < 4; ++ks) {
            int ad = col*NF + (((ks*4 + quad) ^ (col & 7)) << 3);
            size_t off = (size_t)tt*NF + ks*32 + quad*8;
            acc = mfma3(*(short8*)&hH[ad], *(short8*)&hL[ad],
                        *(const short8*)(w2T_h + off), *(const short8*)(w2T_l + off), acc);
        }
        float bias = b2[tt];
        floatx4 o;
        #pragma unroll
        for (int r = 0; r < 4; ++r) o[r] = acc[r] + bias;
        *(floatx4*)(phiT + (size_t)tt*NN + n0 + quad*4) = o;   // transposed store
    }
}

// ---------------- message: block = (graph, 8-atom tile), 768 thr = 12 waves ----------------
// XCD swizzle: all 6 tiles of a graph land on blockIdx == xcd (mod 8).
// Geometry recomputed in-block (no tkG/weG/dirG globals).
// waves 0-3: ds, 4-7: dvv, 8-11: dvs. j-side operands read transposed (float4 over j).
__global__ void __launch_bounds__(768, 1) message_kernel(
        const float* __restrict__ pos,
        const float* __restrict__ sIn, const float* __restrict__ vIn,
        const float* __restrict__ phiT, const float* __restrict__ vT,
        const short* __restrict__ rbfT_h, const short* __restrict__ rbfT_l,
        const float* __restrict__ rbf_b_l,
        float* __restrict__ sOut, float* __restrict__ vOut) {
    __shared__ short tkL[8*NA*64];     // 48 KB, XOR-swizzled 8-short chunks
    __shared__ float red[2*3*NF];      // dvs -> dvv handoff (2 atoms per chunk)
    __shared__ float px[NA], py[NA], pz[NA];
    __shared__ float weL[8][NA];
    __shared__ float dirL[3][8][NA];
    int raw = blockIdx.x;
    int xcd = raw & 7, idx = raw >> 3;           // idx in [0,72)
    int graph = xcd + 8*(idx % 12);
    int itile = idx / 12;                        // [0,6)
    int i0l = itile*8;
    int jbase = graph*NA;
    int t = threadIdx.x;
    int w = t >> 6, lane = t & 63, quad = lane >> 4, col = lane & 15;
    int g = w >> 2, sub = w & 3;
    if (t < NA) {
        px[t] = pos[(jbase+t)*3 + 0];
        py[t] = pos[(jbase+t)*3 + 1];
        pz[t] = pos[(jbase+t)*3 + 2];
    }
    __syncthreads();
    {   // geometry + rbf*w_env -> tk LDS. 2 threads per (atom ii, neighbor j), 32 k-bins each.
        int p = t >> 1, half = t & 1;
        int ii = p / NA, j = p % NA;
        int il = i0l + ii;
        float dx = px[il] - px[j], dy = py[il] - py[j], dz = pz[il] - pz[j];
        float d2 = dx*dx + dy*dy + dz*dz;
        float dd = sqrtf((j == il) ? 1.0f : d2);       // matches where(eye,1,d2)
        bool valid = (j != il) && (dd < CUTF);
        float we = valid ? 0.5f*(cosf(PI_F * dd / CUTF) + 1.0f) : 0.0f;
        if (half == 0) {
            weL[ii][j] = we;
            float inv = 1.0f / dd;
            dirL[0][ii][j] = dx*inv; dirL[1][ii][j] = dy*inv; dirL[2][ii][j] = dz*inv;
        }
        int base = (ii*NA + j) << 6;
        #pragma unroll
        for (int c = 0; c < 4; ++c) {
            short8 h8;
            #pragma unroll
            for (int kk = 0; kk < 8; ++kk) {
                int k = half*32 + c*8 + kk;
                float cen = CUTF * (float)k / 63.0f;
                float df = dd - cen;
                h8[kk] = f2bf(expf(-GAMMA_F * df * df) * we);
            }
            *(short8*)&tkL[base + (((half*4 + c) ^ (j & 7)) << 3)] = h8;
        }
    }
    int fC = sub*32;
    int Tb = g*128 + fC;
    short8 Bh[2][2], Bl[2][2];
    float rb[2];
    #pragma unroll
    for (int nt = 0; nt < 2; ++nt) {
        int tt = Tb + nt*16 + col;
        rb[nt] = rbf_b_l[tt];
        #pragma unroll
        for (int ks = 0; ks < 2; ++ks) {
            size_t off = (size_t)tt*NK + ks*32 + quad*8;
            Bh[nt][ks] = *(const short8*)(rbfT_h + off);
            Bl[nt][ks] = *(const short8*)(rbfT_l + off);
        }
    }
    __syncthreads();
    for (int ic = 0; ic < 4; ++ic) {
        floatx4 C[2][3][2];
        #pragma unroll
        for (int ii = 0; ii < 2; ++ii)
            #pragma unroll
            for (int mt = 0; mt < 3; ++mt)
                #pragma unroll
                for (int nt = 0; nt < 2; ++nt) C[ii][mt][nt] = (floatx4){0.f,0.f,0.f,0.f};
        #pragma unroll
        for (int ii = 0; ii < 2; ++ii) {
            int il = ic*2 + ii;
            #pragma unroll
            for (int mt = 0; mt < 3; ++mt) {
                int j = mt*16 + col;
                #pragma unroll
                for (int ks = 0; ks < 2; ++ks) {
                    short8 a = *(short8*)&tkL[((il*NA + j) << 6) + (((ks*4 + quad) ^ (j & 7)) << 3)];
                    #pragma unroll
                    for (int nt = 0; nt < 2; ++nt)
                        C[ii][mt][nt] = mfma2(a, Bh[nt][ks], Bl[nt][ks], C[ii][mt][nt]);
                }
            }
        }
        float a0[2][2], a1[2][2], a2[2][2], accS[2][2];
        #pragma unroll
        for (int ii = 0; ii < 2; ++ii)
            #pragma unroll
            for (int nt = 0; nt < 2; ++nt) { a0[ii][nt]=0.f; a1[ii][nt]=0.f; a2[ii][nt]=0.f; accS[ii][nt]=0.f; }
        #pragma unroll
        for (int ii = 0; ii < 2; ++ii) {
            int iil = ic*2 + ii;        // local atom for weL/dirL
            #pragma unroll
            for (int mt = 0; mt < 3; ++mt) {
                int jq = mt*16 + quad*4;
                floatx4 we4 = *(const floatx4*)&weL[i0l ? 0 : 0][0] ; // placeholder avoided below
                we4 = *(const floatx4*)&weL[iil][jq];
                if (g == 0) {
                    #pragma unroll
                    for (int nt = 0; nt < 2; ++nt) {
                        int tt = fC + nt*16 + col;
                        floatx4 ph = *(const floatx4*)(phiT + (size_t)tt*NN + jbase + jq);
                        #pragma unroll
                        for (int r = 0; r < 4; ++r) {
                            float Wf = fmaf(rb[nt], we4[r], C[ii][mt][nt][r]);
                            accS[ii][nt] = fmaf(ph[r], Wf, accS[ii][nt]);
                        }
                    }
                } else if (g == 1) {
                    #pragma unroll
                    for (int nt = 0; nt < 2; ++nt) {
                        int f = fC + nt*16 + col;
                        floatx4 ph = *(const floatx4*)(phiT + (size_t)(NF + f)*NN + jbase + jq);
                        floatx4 v0 = *(const floatx4*)(vT + (size_t)(0*NF + f)*NN + jbase + jq);
                        floatx4 v1 = *(const floatx4*)(vT + (size_t)(1*NF + f)*NN + jbase + jq);
                        floatx4 v2 = *(const floatx4*)(vT + (size_t)(2*NF + f)*NN + jbase + jq);
                        #pragma unroll
                        for (int r = 0; r < 4; ++r) {
                            float Wf = fmaf(rb[nt], we4[r], C[ii][mt][nt][r]);
                            float x = ph[r] * Wf;
                            a0[ii][nt] = fmaf(x, v0[r], a0[ii][nt]);
                            a1[ii][nt] = fmaf(x, v1[r], a1[ii][nt]);
                            a2[ii][nt] = fmaf(x, v2[r], a2[ii][nt]);
                        }
                    }
                } else {
                    floatx4 d0 = *(const floatx4*)&dirL[0][iil][jq];
                    floatx4 d1 = *(const floatx4*)&dirL[1][iil][jq];
                    floatx4 d2v = *(const floatx4*)&dirL[2][iil][jq];
                    #pragma unroll
                    for (int nt = 0; nt < 2; ++nt) {
                        int f = fC + nt*16 + col;
                        floatx4 ph = *(const floatx4*)(phiT + (size_t)(2*NF + f)*NN + jbase + jq);
                        #pragma unroll
                        for (int r = 0; r < 4; ++r) {
                            float Wf = fmaf(rb[nt], we4[r], C[ii][mt][nt][r]);
                            float x = ph[r] * Wf;
                            a0[ii][nt] = fmaf(x, d0[r],  a0[ii][nt]);
                            a1[ii][nt] = fmaf(x, d1[r],  a1[ii][nt]);
                            a2[ii][nt] = fmaf(x, d2v[r], a2[ii][nt]);
                        }
                    }
                }
            }
        }
        #pragma unroll
        for (int ii = 0; ii < 2; ++ii) {
            #pragma unroll
            for (int nt = 0; nt < 2; ++nt) {
                if (g == 0) {
                    accS[ii][nt] += __shfl_xor(accS[ii][nt], 16, 64);
                    accS[ii][nt] += __shfl_xor(accS[ii][nt], 32, 64);
                } else {
                    a0[ii][nt] += __shfl_xor(a0[ii][nt], 16, 64); a0[ii][nt] += __shfl_xor(a0[ii][nt], 32, 64);
                    a1[ii][nt] += __shfl_xor(a1[ii][nt], 16, 64); a1[ii][nt] += __shfl_xor(a1[ii][nt], 32, 64);
                    a2[ii][nt] += __shfl_xor(a2[ii][nt], 16, 64); a2[ii][nt] += __shfl_xor(a2[ii][nt], 32, 64);
                }
            }
        }
        if (g == 2 && quad == 0) {
            #pragma unroll
            for (int ii = 0; ii < 2; ++ii)
                #pragma unroll
                for (int nt = 0; nt < 2; ++nt) {
                    int f = fC + nt*16 + col;
                    red[ii*F3 + 0*NF + f] = a0[ii][nt];
                    red[ii*F3 + 1*NF + f] = a1[ii][nt];
                    red[ii*F3 + 2*NF + f] = a2[ii][nt];
                }
        }
        if (g == 0 && quad == 0) {
            #pragma unroll
            for (int ii = 0; ii < 2; ++ii) {
                int i = jbase + i0l + ic*2 + ii;
                #pragma unroll
                for (int nt = 0; nt < 2; ++nt) {
                    int f = fC + nt*16 + col;
                    sOut[(size_t)i*NF + f] = sIn[(size_t)i*NF + f] + accS[ii][nt];
                }
            }
        }
        __syncthreads();
        if (g == 1 && quad == 0) {
            #pragma unroll
            for (int ii = 0; ii < 2; ++ii) {
                int i = jbase + i0l + ic*2 + ii;
                #pragma unroll
                for (int nt = 0; nt < 2; ++nt) {
                    int f = fC + nt*16 + col;
                    #pragma unroll
                    for (int c = 0; c < 3; ++c) {
                        size_t o = (size_t)i*F3 + c*NF + f;
                        float dvs = red[ii*F3 + c*NF + f];
                        float acc = (c == 0) ? a0[ii][nt] : ((c == 1) ? a1[ii][nt] : a2[ii][nt]);
                        vOut[o] = vIn[o] + dvs + acc;
                    }
                }
            }
        }
        __syncthreads();
    }
}

// ---------------- update via MFMA x3: 16 nodes/block, 256 thr; writes v (node-major) + vT ----------------
__global__ void __launch_bounds__(256) update_kernel(
        const short* __restrict__ UT_h, const short* __restrict__ UT_l,
        const short* __restrict__ VT_h, const short* __restrict__ VT_l,
        const short* __restrict__ u1T_h, const short* __restrict__ u1T_l,
        const float* __restrict__ b1,
        const short* __restrict__ u2T_h, const short* __restrict__ u2T_l,
        const float* __restrict__ b2,
        float* __restrict__ s, float* __restrict__ v, float* __restrict__ vT) {
    __shared__ short A1h[48*NF], A1l[48*NF];
    __shared__ short A2h[16*256], A2l[16*256];
    __shared__ short hH[16*NF], hL[16*NF];
    __shared__ float sF[16*132];
    int t = threadIdx.x;
    int w = t >> 6, lane = t & 63, quad = lane >> 4, col = lane & 15;
    int n0 = blockIdx.x * 16;
    int fC = w * 32;
    for (int e = t; e < 16*F3; e += 256) {
        int n = e / F3, cf = e % F3;
        int c = cf >> 7, f = cf & 127;
        float x = v[(size_t)(n0+n)*F3 + cf];
        int row = c*16 + n;
        short h = f2bf(x);
        int ad = row*NF + (((f >> 3) ^ (row & 7)) << 3) + (f & 7);
        A1h[ad] = h; A1l[ad] = f2bf(x - bf2f(h));
    }
    for (int e = t; e < 16*NF; e += 256) {
        int n = e >> 7, f = e & 127;
        float x = s[(size_t)(n0+n)*NF + f];
        sF[n*132 + f] = x;
        short h = f2bf(x);
        int ad = n*256 + (((f >> 3) ^ (n & 7)) << 3) + (f & 7);
        A2h[ad] = h; A2l[ad] = f2bf(x - bf2f(h));
    }
    __syncthreads();
    floatx4 Uacc[3][2], Vacc[3][2];
    #pragma unroll
    for (int mt = 0; mt < 3; ++mt)
        #pragma unroll
        for (int nt = 0; nt < 2; ++nt) { Uacc[mt][nt] = (floatx4){0.f,0.f,0.f,0.f}; Vacc[mt][nt] = (floatx4){0.f,0.f,0.f,0.f}; }
    for (int ks = 0; ks < 4; ++ks) {
        short8 BUh[2], BUl[2], BVh[2], BVl[2];
        #pragma unroll
        for (int nt = 0; nt < 2; ++nt) {
            size_t off = (size_t)(fC + nt*16 + col)*NF + ks*32 + quad*8;
            BUh[nt] = *(const short8*)(UT_h + off); BUl[nt] = *(const short8*)(UT_l + off);
            BVh[nt] = *(const short8*)(VT_h + off); BVl[nt] = *(const short8*)(VT_l + off);
        }
        #pragma unroll
        for (int mt = 0; mt < 3; ++mt) {
            int row = mt*16 + col;
            int ad = row*NF + (((ks*4 + quad) ^ (row & 7)) << 3);
            short8 ah = *(short8*)&A1h[ad], al = *(short8*)&A1l[ad];
            #pragma unroll
            for (int nt = 0; nt < 2; ++nt) {
                Uacc[mt][nt] = mfma3(ah, al, BUh[nt], BUl[nt], Uacc[mt][nt]);
                Vacc[mt][nt] = mfma3(ah, al, BVh[nt], BVl[nt], Vacc[mt][nt]);
            }
        }
    }
    #pragma unroll
    for (int nt = 0; nt < 2; ++nt) {
        int f = fC + nt*16 + col;
        #pragma unroll
        for (int r = 0; r < 4; ++r) {
            int n = quad*4 + r;
            float v0 = Vacc[0][nt][r], v1 = Vacc[1][nt][r], v2 = Vacc[2][nt][r];
            float vn = sqrtf(v0*v0 + v1*v1 + v2*v2 + 1e-8f);
            short h = f2bf(vn);
            int ad = n*256 + ((((128 + f) >> 3) ^ (n & 7)) << 3) + (f & 7);
            A2h[ad] = h; A2l[ad] = f2bf(vn - bf2f(h));
        }
    }
    __syncthreads();
    {
        floatx4 H[2];
        #pragma unroll
        for (int nt = 0; nt < 2; ++nt) H[nt] = (floatx4){0.f,0.f,0.f,0.f};
        for (int ks = 0; ks < 8; ++ks) {
            int ad = col*256 + (((ks*4 + quad) ^ (col & 7)) << 3);
            short8 ah = *(short8*)&A2h[ad], al = *(short8*)&A2l[ad];
            #pragma unroll
            for (int nt = 0; nt < 2; ++nt) {
                size_t off = (size_t)(fC + nt*16 + col)*(2*NF) + ks*32 + quad*8;
                H[nt] = mfma3(ah, al, *(const short8*)(u1T_h + off), *(const short8*)(u1T_l + off), H[nt]);
            }
        }
        #pragma unroll
        for (int nt = 0; nt < 2; ++nt) {
            int f = fC + nt*16 + col;
            float bias = b1[f];
            #pragma unroll
            for (int r = 0; r < 4; ++r) {
                int n = quad*4 + r;
                float hv = silu_f(H[nt][r] + bias);
                short h = f2bf(hv);
                int ad = n*NF + (((f >> 3) ^ (n & 7)) << 3) + (f & 7);
                hH[ad] = h; hL[ad] = f2bf(hv - bf2f(h));
            }
        }
    }
    __syncthreads();
    floatx4 O[3][2];
    #pragma unroll
    for (int gg = 0; gg < 3; ++gg)
        #pragma unroll
        for (int nt = 0; nt < 2; ++nt) O[gg][nt] = (floatx4){0.f,0.f,0.f,0.f};
    for (int ks = 0; ks < 4; ++ks) {
        int ad = col*NF + (((ks*4 + quad) ^ (col & 7)) << 3);
        short8 ah = *(short8*)&hH[ad], al = *(short8*)&hL[ad];
        #pragma unroll
        for (int gg = 0; gg < 3; ++gg)
            #pragma unroll
            for (int nt = 0; nt < 2; ++nt) {
                size_t off = (size_t)(gg*NF + fC + nt*16 + col)*NF + ks*32 + quad*8;
                O[gg][nt] = mfma3(ah, al, *(const short8*)(u2T_h + off), *(const short8*)(u2T_l + off), O[gg][nt]);
            }
    }
    #pragma unroll
    for (int nt = 0; nt < 2; ++nt) {
        int f = fC + nt*16 + col;
        float bavv = b2[f], basv = b2[NF + f], bass = b2[2*NF + f];
        #pragma unroll
        for (int r = 0; r < 4; ++r) {
            int n = quad*4 + r;
            float avv = O[0][nt][r] + bavv;
            float asv = O[1][nt][r] + basv;
            float ass = O[2][nt][r] + bass;
            float dot = Uacc[0][nt][r]*Vacc[0][nt][r] + Uacc[1][nt][r]*Vacc[1][nt][r]
                      + Uacc[2][nt][r]*Vacc[2][nt][r];
            s[(size_t)(n0+n)*NF + f] = sF[n*132 + f] + asv*dot + ass;
            #pragma unroll
            for (int c = 0; c < 3; ++c) {
                int row = c*16 + n;
                int ad = row*NF + (((f >> 3) ^ (row & 7)) << 3) + (f & 7);
                float vold = bf2f(A1h[ad]) + bf2f(A1l[ad]);
                float vnew = vold + avv*Uacc[c][nt][r];
                v[(size_t)(n0+n)*F3 + c*NF + f] = vnew;
                vT[(size_t)(c*NF + f)*NN + n0 + n] = vnew;
            }
        }
    }
}

// ---------------- output head ----------------
__global__ void zero_out_kernel(float* __restrict__ out) {
    out[threadIdx.x] = 0.f;
}

__global__ void out_kernel(const float* __restrict__ s,
                           const float* __restrict__ w1, const float* __restrict__ b1,
                           const float* __restrict__ w2, const float* __restrict__ b2,
                           float* __restrict__ out) {
    int n = blockIdx.x;
    int f = threadIdx.x;
    __shared__ float sh[NF];
    __shared__ float r2[2];
    sh[f] = s[n*NF + f];
    __syncthreads();
    float acc = b1[f];
    for (int g = 0; g < NF; ++g) acc = fmaf(sh[g], w1[g*NF + f], acc);
    float p = silu_f(acc) * w2[f];
    #pragma unroll
    for (int off = 32; off > 0; off >>= 1) p += __shfl_down(p, off, 64);
    if ((f & 63) == 0) r2[f >> 6] = p;
    __syncthreads();
    if (f == 0) atomicAdd(&out[n / NA], r2[0] + r2[1] + b2[0]);
}

extern "C" void kernel_launch(void* const* d_in, const int* in_sizes, int n_in,
                              void* d_out, int out_size, void* d_ws, size_t ws_size,
                              hipStream_t stream) {
    (void)in_sizes; (void)n_in; (void)out_size; (void)ws_size;
    const float* pos      = (const float*)d_in[1];
    const int*   node_atom= (const int*)  d_in[3];
    const float* emb      = (const float*)d_in[4];
    const float* msg_w1   = (const float*)d_in[5];
    const float* msg_b1   = (const float*)d_in[6];
    const float* msg_w2   = (const float*)d_in[7];
    const float* msg_b2   = (const float*)d_in[8];
    const float* rbf_w    = (const float*)d_in[9];
    const float* rbf_b    = (const float*)d_in[10];
    const float* upd_U    = (const float*)d_in[11];
    const float* upd_V    = (const float*)d_in[12];
    const float* upd_w1   = (const float*)d_in[13];
    const float* upd_b1   = (const float*)d_in[14];
    const float* upd_w2   = (const float*)d_in[15];
    const float* upd_b2   = (const float*)d_in[16];
    const float* out_w1   = (const float*)d_in[17];
    const float* out_b1   = (const float*)d_in[18];
    const float* out_w2   = (const float*)d_in[19];
    const float* out_b2   = (const float*)d_in[20];
    float* out = (float*)d_out;

    float* ws   = (float*)d_ws;
    float* sA   = ws; ws += (size_t)NN*NF;
    float* sB   = ws; ws += (size_t)NN*NF;
    float* vA   = ws; ws += (size_t)NN*F3;
    float* vB   = ws; ws += (size_t)NN*F3;
    float* phiT = ws; ws += (size_t)F3*NN;
    float* vT   = ws; ws += (size_t)F3*NN;
    short* sp    = (short*)ws;
    short* w1T_h = sp; sp += (size_t)NL*NF*NF;
    short* w1T_l = sp; sp += (size_t)NL*NF*NF;
    short* w2T_h = sp; sp += (size_t)NL*F3*NF;
    short* w2T_l = sp; sp += (size_t)NL*F3*NF;
    short* rbfT_h= sp; sp += (size_t)NL*F3*NK;
    short* rbfT_l= sp; sp += (size_t)NL*F3*NK;
    short* UT_h  = sp; sp += (size_t)NL*NF*NF;
    short* UT_l  = sp; sp += (size_t)NL*NF*NF;
    short* VT_h  = sp; sp += (size_t)NL*NF*NF;
    short* VT_l  = sp; sp += (size_t)NL*NF*NF;
    short* u1T_h = sp; sp += (size_t)NL*NF*2*NF;
    short* u1T_l = sp; sp += (size_t)NL*NF*2*NF;
    short* u2T_h = sp; sp += (size_t)NL*F3*NF;
    short* u2T_l = sp; sp += (size_t)NL*F3*NF;

    prep_kernel<<<dim3(NL*384, 7), 64, 0, stream>>>(msg_w1, msg_w2, rbf_w, upd_U, upd_V, upd_w1, upd_w2,
                                                    w1T_h, w1T_l, w2T_h, w2T_l, rbfT_h, rbfT_l,
                                                    UT_h, UT_l, VT_h, VT_l, u1T_h, u1T_l, u2T_h, u2T_l);
    init_kernel<<<NN, NF, 0, stream>>>(emb, node_atom, sA, vA);
    zero_kernel<<<(F3*NN)/256, 256, 0, stream>>>(vT);

    float* sC = sA; float* vC = vA; float* sN = sB; float* vN = vB;
    for (int l = 0; l < NL; ++l) {
        phi_kernel<<<NN/16, 128, 0, stream>>>(sC, w1T_h + (size_t)l*NF*NF, w1T_l + (size_t)l*NF*NF,
                                              msg_b1 + (size_t)l*NF,
                                              w2T_h + (size_t)l*F3*NF, w2T_l + (size_t)l*F3*NF,
                                              msg_b2 + (size_t)l*F3, phiT);
        message_kernel<<<NB*6, 768, 0, stream>>>(pos, sC, vC, phiT, vT,
                                                 rbfT_h + (size_t)l*F3*NK, rbfT_l + (size_t)l*F3*NK,
                                                 rbf_b + (size_t)l*F3, sN, vN);
        update_kernel<<<NN/16, 256, 0, stream>>>(UT_h + (size_t)l*NF*NF, UT_l + (size_t)l*NF*NF,
                                                 VT_h + (size_t)l*NF*NF, VT_l + (size_t)l*NF*NF,
                                                 u1T_h + (size_t)l*NF*2*NF, u1T_l + (size_t)l*NF*2*NF,
                                                 upd_b1 + (size_t)l*NF,
                                                 u2T_h + (size_t)l*F3*NF, u2T_l + (size_t)l*F3*NF,
                                                 upd_b2 + (size_t)l*F3, sN, vN, vT);
        float* tp;
        tp = sC; sC = sN; sN = tp;
        tp = vC; vC = vN; vN = tp;
    }
    zero_out_kernel<<<1, NB, 0, stream>>>(out);
    out_kernel<<<NN, NF, 0, stream>>>(sC, out_w1, out_b1, out_w2, out_b2, out);
}

// Round 6
// 843.810 us; speedup vs baseline: 1.8463x; 1.7266x over previous
//
#include <hip/hip_runtime.h>
#include <math.h>

#define NB 96
#define NA 48
#define NF 128
#define NK 64
#define NL 6
#define NN (NB*NA)     // 4608 nodes
#define F3 (3*NF)      // 384
#define CUTF 5.0f
#define GAMMA_F ((float)(1.0 / (0.006103515625 + 1e-9)))
#define PI_F 3.14159265358979323846f

typedef __attribute__((ext_vector_type(8))) short short8;
typedef __attribute__((ext_vector_type(4))) float floatx4;

__device__ __forceinline__ float silu_f(float x) { return x / (1.0f + expf(-x)); }

__device__ __forceinline__ short f2bf(float x) {
    unsigned u = __builtin_bit_cast(unsigned, x);
    unsigned r = (u + 0x7fffu + ((u >> 16) & 1u)) >> 16;   // RNE
    return (short)r;
}
__device__ __forceinline__ float bf2f(short h) {
    unsigned u = ((unsigned)(unsigned short)h) << 16;
    return __builtin_bit_cast(float, u);
}
__device__ __forceinline__ floatx4 mfma2(short8 a, short8 bh, short8 bl, floatx4 c) {
    c = __builtin_amdgcn_mfma_f32_16x16x32_bf16(a, bh, c, 0, 0, 0);
    c = __builtin_amdgcn_mfma_f32_16x16x32_bf16(a, bl, c, 0, 0, 0);
    return c;
}
__device__ __forceinline__ floatx4 mfma3(short8 ah, short8 al, short8 bh, short8 bl, floatx4 c) {
    c = __builtin_amdgcn_mfma_f32_16x16x32_bf16(ah, bh, c, 0, 0, 0);
    c = __builtin_amdgcn_mfma_f32_16x16x32_bf16(al, bh, c, 0, 0, 0);
    c = __builtin_amdgcn_mfma_f32_16x16x32_bf16(ah, bl, c, 0, 0, 0);
    return c;
}

// ---------------- fused prep: weights -> bf16 hi/lo in MFMA B-FRAGMENT ORDER ----------------
// frag layout: off = (((n>>4)*(K/32) + (k>>5))*4 + ((k>>3)&3))*128 + (n&15)*8 + (k&7)
// -> a wave loading (t16, ks) reads 1 KB contiguous (lane (quad,col) at +quad*128+col*8).
__global__ void prep_kernel(const float* __restrict__ msg_w1, const float* __restrict__ msg_w2,
                            const float* __restrict__ rbf_w, const float* __restrict__ upd_U,
                            const float* __restrict__ upd_V, const float* __restrict__ upd_w1,
                            const float* __restrict__ upd_w2,
                            short* w1T_h, short* w1T_l, short* w2T_h, short* w2T_l,
                            short* rbfT_h, short* rbfT_l, short* UT_h, short* UT_l,
                            short* VT_h, short* VT_l, short* u1T_h, short* u1T_l,
                            short* u2T_h, short* u2T_l) {
    int m = blockIdx.y;
    int l = blockIdx.x / 384;
    int n = blockIdx.x % 384;
    const float* src; short* dh; short* dl; int K, N;
    switch (m) {
      case 0: src = msg_w1; dh = w1T_h; dl = w1T_l; K = NF;   N = NF; break;
      case 1: src = msg_w2; dh = w2T_h; dl = w2T_l; K = NF;   N = F3; break;
      case 2: src = rbf_w;  dh = rbfT_h;dl = rbfT_l;K = NK;   N = F3; break;
      case 3: src = upd_U;  dh = UT_h;  dl = UT_l;  K = NF;   N = NF; break;
      case 4: src = upd_V;  dh = VT_h;  dl = VT_l;  K = NF;   N = NF; break;
      case 5: src = upd_w1; dh = u1T_h; dl = u1T_l; K = 2*NF; N = NF; break;
      default:src = upd_w2; dh = u2T_h; dl = u2T_l; K = NF;   N = F3; break;
    }
    if (n >= N) return;
    for (int k = threadIdx.x; k < K; k += 64) {
        float x = src[((size_t)l*K + k)*N + n];
        short h = f2bf(x);
        size_t off = (size_t)l*N*K
                   + (size_t)((((n>>4)*(K>>5) + (k>>5))*4 + ((k>>3)&3))*128 + (n&15)*8 + (k&7));
        dh[off] = h;
        dl[off] = f2bf(x - bf2f(h));
    }
}

// ---------------- init ----------------
__global__ void init_kernel(const float* __restrict__ emb, const int* __restrict__ node_atom,
                            float* __restrict__ s, float* __restrict__ v) {
    int n = blockIdx.x, f = threadIdx.x;
    int a = node_atom[n];
    s[n*NF + f] = emb[a*NF + f];
    v[n*F3 + f] = 0.f;
    v[n*F3 + NF + f] = 0.f;
    v[n*F3 + 2*NF + f] = 0.f;
}

__global__ void zero_kernel(float* __restrict__ p) {
    p[(size_t)blockIdx.x * blockDim.x + threadIdx.x] = 0.f;
}

// ---------------- phi MLP via MFMA x3 -> TRANSPOSED phiT[t][node] ----------------
__global__ void __launch_bounds__(128) phi_kernel(const float* __restrict__ sIn,
                                                  const short* __restrict__ w1T_h, const short* __restrict__ w1T_l,
                                                  const float* __restrict__ b1,
                                                  const short* __restrict__ w2T_h, const short* __restrict__ w2T_l,
                                                  const float* __restrict__ b2,
                                                  float* __restrict__ phiT) {
    __shared__ short sH[16*NF], sL[16*NF];
    __shared__ short hH[16*NF], hL[16*NF];
    int t = threadIdx.x;
    int w = t >> 6, lane = t & 63, quad = lane >> 4, col = lane & 15;
    int n0 = blockIdx.x * 16;
    for (int e = t; e < 16*NF; e += 128) {
        int n = e >> 7, f = e & 127;
        float x = sIn[(size_t)(n0+n)*NF + f];
        short h = f2bf(x);
        int ad = n*NF + (((f >> 3) ^ (n & 7)) << 3) + (f & 7);
        sH[ad] = h; sL[ad] = f2bf(x - bf2f(h));
    }
    __syncthreads();
    #pragma unroll
    for (int nt = 0; nt < 4; ++nt) {
        int fh = w*64 + nt*16 + col;
        floatx4 acc = (floatx4){0.f,0.f,0.f,0.f};
        #pragma unroll
        for (int ks = 0; ks < 4; ++ks) {
            int ad = col*NF + (((ks*4 + quad) ^ (col & 7)) << 3);
            size_t off = (size_t)((((w*4 + nt)*4 + ks)*4 + quad)*128) + col*8;
            acc = mfma3(*(short8*)&sH[ad], *(short8*)&sL[ad],
                        *(const short8*)(w1T_h + off), *(const short8*)(w1T_l + off), acc);
        }
        float bias = b1[fh];
        #pragma unroll
        for (int r = 0; r < 4; ++r) {
            int n = quad*4 + r;
            float hv = silu_f(acc[r] + bias);
            short h = f2bf(hv);
            int ad = n*NF + (((fh >> 3) ^ (n & 7)) << 3) + (fh & 7);
            hH[ad] = h; hL[ad] = f2bf(hv - bf2f(h));
        }
    }
    __syncthreads();
    #pragma unroll
    for (int nt = 0; nt < 12; ++nt) {
        int tt = w*192 + nt*16 + col;
        floatx4 acc = (floatx4){0.f,0.f,0.f,0.f};
        #pragma unroll
        for (int ks = 0; ks < 4; ++ks) {
            int ad = col*NF + (((ks*4 + quad) ^ (col & 7)) << 3);
            size_t off = (size_t)((((w*12 + nt)*4 + ks)*4 + quad)*128) + col*8;
            acc = mfma3(*(short8*)&hH[ad], *(short8*)&hL[ad],
                        *(const short8*)(w2T_h + off), *(const short8*)(w2T_l + off), acc);
        }
        float bias = b2[tt];
        floatx4 o;
        #pragma unroll
        for (int r = 0; r < 4; ++r) o[r] = acc[r] + bias;
        *(floatx4*)(phiT + (size_t)tt*NN + n0 + quad*4) = o;   // transposed store
    }
}

// ---------------- message: block = (graph, 4-atom tile), 512 thr = 8 waves ----------------
// Wave w owns feature chunk f = w*16+col and computes ALL THREE groups (ds+dvv+dvs):
// no wave specialization, no in-loop barriers, j-side operands hoisted to registers
// once per block (atom-independent). XCD swizzle keeps a graph's 12 tiles on one XCD.
__global__ void __launch_bounds__(512) message_kernel(
        const float* __restrict__ pos,
        const float* __restrict__ sIn, const float* __restrict__ vIn,
        const float* __restrict__ phiT, const float* __restrict__ vT,
        const short* __restrict__ rbfT_h, const short* __restrict__ rbfT_l,
        const float* __restrict__ rbf_b_l,
        float* __restrict__ sOut, float* __restrict__ vOut) {
    __shared__ short tkL[4*NA*64];     // 24 KB, XOR-swizzled 8-short chunks
    __shared__ float px[NA], py[NA], pz[NA];
    __shared__ float weL[4][NA];
    __shared__ float dirL[3][4][NA];
    int raw = blockIdx.x;
    int xcd = raw & 7, idx = raw >> 3;           // idx in [0,144)
    int graph = xcd + 8*(idx % 12);
    int itile = idx / 12;                        // [0,12)
    int i0l = itile*4;
    int jbase = graph*NA;
    int t = threadIdx.x;
    int w = t >> 6, lane = t & 63, quad = lane >> 4, col = lane & 15;
    if (t < NA) {
        px[t] = pos[(jbase+t)*3 + 0];
        py[t] = pos[(jbase+t)*3 + 1];
        pz[t] = pos[(jbase+t)*3 + 2];
    }
    __syncthreads();
    if (t < 384) {   // geometry: 2 threads per (atom ii, neighbor j), 32 k-bins each
        int p = t >> 1, half = t & 1;
        int ii = p / NA, j = p % NA;
        int il = i0l + ii;
        float dx = px[il] - px[j], dy = py[il] - py[j], dz = pz[il] - pz[j];
        float d2 = dx*dx + dy*dy + dz*dz;
        float dd = sqrtf((j == il) ? 1.0f : d2);       // matches where(eye,1,d2)
        bool valid = (j != il) && (dd < CUTF);
        float we = valid ? 0.5f*(cosf(PI_F * dd / CUTF) + 1.0f) : 0.0f;
        if (half == 0) {
            weL[ii][j] = we;
            float inv = 1.0f / dd;
            dirL[0][ii][j] = dx*inv; dirL[1][ii][j] = dy*inv; dirL[2][ii][j] = dz*inv;
        }
        int base = (ii*NA + j) << 6;
        #pragma unroll
        for (int c = 0; c < 4; ++c) {
            short8 h8;
            #pragma unroll
            for (int kk = 0; kk < 8; ++kk) {
                int k = half*32 + c*8 + kk;
                float cen = CUTF * (float)k / 63.0f;
                float df = dd - cen;
                h8[kk] = f2bf(expf(-GAMMA_F * df * df) * we);
            }
            *(short8*)&tkL[base + (((half*4 + c) ^ (j & 7)) << 3)] = h8;
        }
    }
    int f = w*16 + col;                              // this lane's feature (one per col)
    float rb0 = rbf_b_l[f], rb1 = rbf_b_l[NF+f], rb2 = rbf_b_l[2*NF+f];
    // hoisted j-side operands (atom-independent): float4 over j = mt*16+quad*4..+4
    floatx4 ph0[3], ph1[3], ph2[3], vj0[3], vj1[3], vj2[3];
    #pragma unroll
    for (int mt = 0; mt < 3; ++mt) {
        int jq = jbase + mt*16 + quad*4;
        ph0[mt] = *(const floatx4*)(phiT + (size_t)f*NN + jq);
        ph1[mt] = *(const floatx4*)(phiT + (size_t)(NF+f)*NN + jq);
        ph2[mt] = *(const floatx4*)(phiT + (size_t)(2*NF+f)*NN + jq);
        vj0[mt] = *(const floatx4*)(vT + (size_t)(0*NF+f)*NN + jq);
        vj1[mt] = *(const floatx4*)(vT + (size_t)(1*NF+f)*NN + jq);
        vj2[mt] = *(const floatx4*)(vT + (size_t)(2*NF+f)*NN + jq);
    }
    __syncthreads();
    for (int ia = 0; ia < 4; ++ia) {
        floatx4 C[3][3];
        #pragma unroll
        for (int g = 0; g < 3; ++g)
            #pragma unroll
            for (int mt = 0; mt < 3; ++mt) C[g][mt] = (floatx4){0.f,0.f,0.f,0.f};
        #pragma unroll
        for (int mt = 0; mt < 3; ++mt) {
            int j = mt*16 + col;
            #pragma unroll
            for (int ks = 0; ks < 2; ++ks) {
                short8 a = *(short8*)&tkL[((ia*NA + j) << 6) + (((ks*4 + quad) ^ (j & 7)) << 3)];
                #pragma unroll
                for (int g = 0; g < 3; ++g) {
                    size_t off = (size_t)((((g*8 + w)*2 + ks)*4 + quad)*128) + col*8;
                    C[g][mt] = mfma2(a, *(const short8*)(rbfT_h + off),
                                        *(const short8*)(rbfT_l + off), C[g][mt]);
                }
            }
        }
        float accS = 0.f, av0 = 0.f, av1 = 0.f, av2 = 0.f;
        #pragma unroll
        for (int mt = 0; mt < 3; ++mt) {
            int jq = mt*16 + quad*4;
            floatx4 we4 = *(const floatx4*)&weL[ia][jq];
            floatx4 d0 = *(const floatx4*)&dirL[0][ia][jq];
            floatx4 d1 = *(const floatx4*)&dirL[1][ia][jq];
            floatx4 d2 = *(const floatx4*)&dirL[2][ia][jq];
            #pragma unroll
            for (int r = 0; r < 4; ++r) {
                float Wf0 = fmaf(rb0, we4[r], C[0][mt][r]);
                accS = fmaf(ph0[mt][r], Wf0, accS);
                float Wf1 = fmaf(rb1, we4[r], C[1][mt][r]);
                float x1 = ph1[mt][r] * Wf1;
                av0 = fmaf(x1, vj0[mt][r], av0);
                av1 = fmaf(x1, vj1[mt][r], av1);
                av2 = fmaf(x1, vj2[mt][r], av2);
                float Wf2 = fmaf(rb2, we4[r], C[2][mt][r]);
                float x2 = ph2[mt][r] * Wf2;
                av0 = fmaf(x2, d0[r], av0);
                av1 = fmaf(x2, d1[r], av1);
                av2 = fmaf(x2, d2[r], av2);
            }
        }
        accS += __shfl_xor(accS, 16, 64); accS += __shfl_xor(accS, 32, 64);
        av0 += __shfl_xor(av0, 16, 64);   av0 += __shfl_xor(av0, 32, 64);
        av1 += __shfl_xor(av1, 16, 64);   av1 += __shfl_xor(av1, 32, 64);
        av2 += __shfl_xor(av2, 16, 64);   av2 += __shfl_xor(av2, 32, 64);
        if (quad == 0) {
            int i = jbase + i0l + ia;
            sOut[(size_t)i*NF + f]        = sIn[(size_t)i*NF + f]        + accS;
            vOut[(size_t)i*F3 + f]        = vIn[(size_t)i*F3 + f]        + av0;
            vOut[(size_t)i*F3 + NF + f]   = vIn[(size_t)i*F3 + NF + f]   + av1;
            vOut[(size_t)i*F3 + 2*NF + f] = vIn[(size_t)i*F3 + 2*NF + f] + av2;
        }
    }
}

// ---------------- update via MFMA x3: 16 nodes/block, 256 thr; writes v + vT ----------------
__global__ void __launch_bounds__(256) update_kernel(
        const short* __restrict__ UT_h, const short* __restrict__ UT_l,
        const short* __restrict__ VT_h, const short* __restrict__ VT_l,
        const short* __restrict__ u1T_h, const short* __restrict__ u1T_l,
        const float* __restrict__ b1,
        const short* __restrict__ u2T_h, const short* __restrict__ u2T_l,
        const float* __restrict__ b2,
        float* __restrict__ s, float* __restrict__ v, float* __restrict__ vT) {
    __shared__ short A1h[48*NF], A1l[48*NF];
    __shared__ short A2h[16*256], A2l[16*256];
    __shared__ short hH[16*NF], hL[16*NF];
    __shared__ float sF[16*132];
    int t = threadIdx.x;
    int w = t >> 6, lane = t & 63, quad = lane >> 4, col = lane & 15;
    int n0 = blockIdx.x * 16;
    int fC = w * 32;
    for (int e = t; e < 16*F3; e += 256) {
        int n = e / F3, cf = e % F3;
        int c = cf >> 7, f = cf & 127;
        float x = v[(size_t)(n0+n)*F3 + cf];
        int row = c*16 + n;
        short h = f2bf(x);
        int ad = row*NF + (((f >> 3) ^ (row & 7)) << 3) + (f & 7);
        A1h[ad] = h; A1l[ad] = f2bf(x - bf2f(h));
    }
    for (int e = t; e < 16*NF; e += 256) {
        int n = e >> 7, f = e & 127;
        float x = s[(size_t)(n0+n)*NF + f];
        sF[n*132 + f] = x;
        short h = f2bf(x);
        int ad = n*256 + (((f >> 3) ^ (n & 7)) << 3) + (f & 7);
        A2h[ad] = h; A2l[ad] = f2bf(x - bf2f(h));
    }
    __syncthreads();
    floatx4 Uacc[3][2], Vacc[3][2];
    #pragma unroll
    for (int mt = 0; mt < 3; ++mt)
        #pragma unroll
        for (int nt = 0; nt < 2; ++nt) { Uacc[mt][nt] = (floatx4){0.f,0.f,0.f,0.f}; Vacc[mt][nt] = (floatx4){0.f,0.f,0.f,0.f}; }
    for (int ks = 0; ks < 4; ++ks) {
        short8 BUh[2], BUl[2], BVh[2], BVl[2];
        #pragma unroll
        for (int nt = 0; nt < 2; ++nt) {
            size_t off = (size_t)((((w*2 + nt)*4 + ks)*4 + quad)*128) + col*8;
            BUh[nt] = *(const short8*)(UT_h + off); BUl[nt] = *(const short8*)(UT_l + off);
            BVh[nt] = *(const short8*)(VT_h + off); BVl[nt] = *(const short8*)(VT_l + off);
        }
        #pragma unroll
        for (int mt = 0; mt < 3; ++mt) {
            int row = mt*16 + col;
            int ad = row*NF + (((ks*4 + quad) ^ (row & 7)) << 3);
            short8 ah = *(short8*)&A1h[ad], al = *(short8*)&A1l[ad];
            #pragma unroll
            for (int nt = 0; nt < 2; ++nt) {
                Uacc[mt][nt] = mfma3(ah, al, BUh[nt], BUl[nt], Uacc[mt][nt]);
                Vacc[mt][nt] = mfma3(ah, al, BVh[nt], BVl[nt], Vacc[mt][nt]);
            }
        }
    }
    #pragma unroll
    for (int nt = 0; nt < 2; ++nt) {
        int f = fC + nt*16 + col;
        #pragma unroll
        for (int r = 0; r < 4; ++r) {
            int n = quad*4 + r;
            float v0 = Vacc[0][nt][r], v1 = Vacc[1][nt][r], v2 = Vacc[2][nt][r];
            float vn = sqrtf(v0*v0 + v1*v1 + v2*v2 + 1e-8f);
            short h = f2bf(vn);
            int ad = n*256 + ((((128 + f) >> 3) ^ (n & 7)) << 3) + (f & 7);
            A2h[ad] = h; A2l[ad] = f2bf(vn - bf2f(h));
        }
    }
    __syncthreads();
    {
        floatx4 H[2];
        #pragma unroll
        for (int nt = 0; nt < 2; ++nt) H[nt] = (floatx4){0.f,0.f,0.f,0.f};
        for (int ks = 0; ks < 8; ++ks) {
            int ad = col*256 + (((ks*4 + quad) ^ (col & 7)) << 3);
            short8 ah = *(short8*)&A2h[ad], al = *(short8*)&A2l[ad];
            #pragma unroll
            for (int nt = 0; nt < 2; ++nt) {
                size_t off = (size_t)((((w*2 + nt)*8 + ks)*4 + quad)*128) + col*8;
                H[nt] = mfma3(ah, al, *(const short8*)(u1T_h + off), *(const short8*)(u1T_l + off), H[nt]);
            }
        }
        #pragma unroll
        for (int nt = 0; nt < 2; ++nt) {
            int f = fC + nt*16 + col;
            float bias = b1[f];
            #pragma unroll
            for (int r = 0; r < 4; ++r) {
                int n = quad*4 + r;
                float hv = silu_f(H[nt][r] + bias);
                short h = f2bf(hv);
                int ad = n*NF + (((f >> 3) ^ (n & 7)) << 3) + (f & 7);
                hH[ad] = h; hL[ad] = f2bf(hv - bf2f(h));
            }
        }
    }
    __syncthreads();
    floatx4 O[3][2];
    #pragma unroll
    for (int gg = 0; gg < 3; ++gg)
        #pragma unroll
        for (int nt = 0; nt < 2; ++nt) O[gg][nt] = (floatx4){0.f,0.f,0.f,0.f};
    for (int ks = 0; ks < 4; ++ks) {
        int ad = col*NF + (((ks*4 + quad) ^ (col & 7)) << 3);
        short8 ah = *(short8*)&hH[ad], al = *(short8*)&hL[ad];
        #pragma unroll
        for (int gg = 0; gg < 3; ++gg)
            #pragma unroll
            for (int nt = 0; nt < 2; ++nt) {
                size_t off = (size_t)((((gg*8 + w*2 + nt)*4 + ks)*4 + quad)*128) + col*8;
                O[gg][nt] = mfma3(ah, al, *(const short8*)(u2T_h + off), *(const short8*)(u2T_l + off), O[gg][nt]);
            }
    }
    #pragma unroll
    for (int nt = 0; nt < 2; ++nt) {
        int f = fC + nt*16 + col;
        float bavv = b2[f], basv = b2[NF + f], bass = b2[2*NF + f];
        #pragma unroll
        for (int r = 0; r < 4; ++r) {
            int n = quad*4 + r;
            float avv = O[0][nt][r] + bavv;
            float asv = O[1][nt][r] + basv;
            float ass = O[2][nt][r] + bass;
            float dot = Uacc[0][nt][r]*Vacc[0][nt][r] + Uacc[1][nt][r]*Vacc[1][nt][r]
                      + Uacc[2][nt][r]*Vacc[2][nt][r];
            s[(size_t)(n0+n)*NF + f] = sF[n*132 + f] + asv*dot + ass;
            #pragma unroll
            for (int c = 0; c < 3; ++c) {
                int row = c*16 + n;
                int ad = row*NF + (((f >> 3) ^ (row & 7)) << 3) + (f & 7);
                float vold = bf2f(A1h[ad]) + bf2f(A1l[ad]);
                float vnew = vold + avv*Uacc[c][nt][r];
                v[(size_t)(n0+n)*F3 + c*NF + f] = vnew;
                vT[(size_t)(c*NF + f)*NN + n0 + n] = vnew;
            }
        }
    }
}

// ---------------- output head ----------------
__global__ void zero_out_kernel(float* __restrict__ out) {
    out[threadIdx.x] = 0.f;
}

__global__ void out_kernel(const float* __restrict__ s,
                           const float* __restrict__ w1, const float* __restrict__ b1,
                           const float* __restrict__ w2, const float* __restrict__ b2,
                           float* __restrict__ out) {
    int n = blockIdx.x;
    int f = threadIdx.x;
    __shared__ float sh[NF];
    __shared__ float r2[2];
    sh[f] = s[n*NF + f];
    __syncthreads();
    float acc = b1[f];
    for (int g = 0; g < NF; ++g) acc = fmaf(sh[g], w1[g*NF + f], acc);
    float p = silu_f(acc) * w2[f];
    #pragma unroll
    for (int off = 32; off > 0; off >>= 1) p += __shfl_down(p, off, 64);
    if ((f & 63) == 0) r2[f >> 6] = p;
    __syncthreads();
    if (f == 0) atomicAdd(&out[n / NA], r2[0] + r2[1] + b2[0]);
}

extern "C" void kernel_launch(void* const* d_in, const int* in_sizes, int n_in,
                              void* d_out, int out_size, void* d_ws, size_t ws_size,
                              hipStream_t stream) {
    (void)in_sizes; (void)n_in; (void)out_size; (void)ws_size;
    const float* pos      = (const float*)d_in[1];
    const int*   node_atom= (const int*)  d_in[3];
    const float* emb      = (const float*)d_in[4];
    const float* msg_w1   = (const float*)d_in[5];
    const float* msg_b1   = (const float*)d_in[6];
    const float* msg_w2   = (const float*)d_in[7];
    const float* msg_b2   = (const float*)d_in[8];
    const float* rbf_w    = (const float*)d_in[9];
    const float* rbf_b    = (const float*)d_in[10];
    const float* upd_U    = (const float*)d_in[11];
    const float* upd_V    = (const float*)d_in[12];
    const float* upd_w1   = (const float*)d_in[13];
    const float* upd_b1   = (const float*)d_in[14];
    const float* upd_w2   = (const float*)d_in[15];
    const float* upd_b2   = (const float*)d_in[16];
    const float* out_w1   = (const float*)d_in[17];
    const float* out_b1   = (const float*)d_in[18];
    const float* out_w2   = (const float*)d_in[19];
    const float* out_b2   = (const float*)d_in[20];
    float* out = (float*)d_out;

    float* ws   = (float*)d_ws;
    float* sA   = ws; ws += (size_t)NN*NF;
    float* sB   = ws; ws += (size_t)NN*NF;
    float* vA   = ws; ws += (size_t)NN*F3;
    float* vB   = ws; ws += (size_t)NN*F3;
    float* phiT = ws; ws += (size_t)F3*NN;
    float* vT   = ws; ws += (size_t)F3*NN;
    short* sp    = (short*)ws;
    short* w1T_h = sp; sp += (size_t)NL*NF*NF;
    short* w1T_l = sp; sp += (size_t)NL*NF*NF;
    short* w2T_h = sp; sp += (size_t)NL*F3*NF;
    short* w2T_l = sp; sp += (size_t)NL*F3*NF;
    short* rbfT_h= sp; sp += (size_t)NL*F3*NK;
    short* rbfT_l= sp; sp += (size_t)NL*F3*NK;
    short* UT_h  = sp; sp += (size_t)NL*NF*NF;
    short* UT_l  = sp; sp += (size_t)NL*NF*NF;
    short* VT_h  = sp; sp += (size_t)NL*NF*NF;
    short* VT_l  = sp; sp += (size_t)NL*NF*NF;
    short* u1T_h = sp; sp += (size_t)NL*NF*2*NF;
    short* u1T_l = sp; sp += (size_t)NL*NF*2*NF;
    short* u2T_h = sp; sp += (size_t)NL*F3*NF;
    short* u2T_l = sp; sp += (size_t)NL*F3*NF;

    prep_kernel<<<dim3(NL*384, 7), 64, 0, stream>>>(msg_w1, msg_w2, rbf_w, upd_U, upd_V, upd_w1, upd_w2,
                                                    w1T_h, w1T_l, w2T_h, w2T_l, rbfT_h, rbfT_l,
                                                    UT_h, UT_l, VT_h, VT_l, u1T_h, u1T_l, u2T_h, u2T_l);
    init_kernel<<<NN, NF, 0, stream>>>(emb, node_atom, sA, vA);
    zero_kernel<<<(F3*NN)/256, 256, 0, stream>>>(vT);

    float* sC = sA; float* vC = vA; float* sN = sB; float* vN = vB;
    for (int l = 0; l < NL; ++l) {
        phi_kernel<<<NN/16, 128, 0, stream>>>(sC, w1T_h + (size_t)l*NF*NF, w1T_l + (size_t)l*NF*NF,
                                              msg_b1 + (size_t)l*NF,
                                              w2T_h + (size_t)l*F3*NF, w2T_l + (size_t)l*F3*NF,
                                              msg_b2 + (size_t)l*F3, phiT);
        message_kernel<<<NB*12, 512, 0, stream>>>(pos, sC, vC, phiT, vT,
                                                  rbfT_h + (size_t)l*F3*NK, rbfT_l + (size_t)l*F3*NK,
                                                  rbf_b + (size_t)l*F3, sN, vN);
        update_kernel<<<NN/16, 256, 0, stream>>>(UT_h + (size_t)l*NF*NF, UT_l + (size_t)l*NF*NF,
                                                 VT_h + (size_t)l*NF*NF, VT_l + (size_t)l*NF*NF,
                                                 u1T_h + (size_t)l*NF*2*NF, u1T_l + (size_t)l*NF*2*NF,
                                                 upd_b1 + (size_t)l*NF,
                                                 u2T_h + (size_t)l*F3*NF, u2T_l + (size_t)l*F3*NF,
                                                 upd_b2 + (size_t)l*F3, sN, vN, vT);
        float* tp;
        tp = sC; sC = sN; sN = tp;
        tp = vC; vC = vN; vN = tp;
    }
    zero_out_kernel<<<1, NB, 0, stream>>>(out);
    out_kernel<<<NN, NF, 0, stream>>>(sC, out_w1, out_b1, out_w2, out_b2, out);
}

// Round 7
// 789.805 us; speedup vs baseline: 1.9726x; 1.0684x over previous
//
#include <hip/hip_runtime.h>
#include <math.h>

#define NB 96
#define NA 48
#define NF 128
#define NK 64
#define NL 6
#define NN (NB*NA)     // 4608 nodes
#define F3 (3*NF)      // 384
#define CUTF 5.0f
#define GAMMA_F ((float)(1.0 / (0.006103515625 + 1e-9)))
#define PI_F 3.14159265358979323846f

typedef __attribute__((ext_vector_type(8))) short short8;
typedef __attribute__((ext_vector_type(4))) float floatx4;

__device__ __forceinline__ float silu_f(float x) { return x / (1.0f + expf(-x)); }

__device__ __forceinline__ short f2bf(float x) {
    unsigned u = __builtin_bit_cast(unsigned, x);
    unsigned r = (u + 0x7fffu + ((u >> 16) & 1u)) >> 16;   // RNE
    return (short)r;
}
__device__ __forceinline__ float bf2f(short h) {
    unsigned u = ((unsigned)(unsigned short)h) << 16;
    return __builtin_bit_cast(float, u);
}
__device__ __forceinline__ floatx4 mfma2(short8 a, short8 bh, short8 bl, floatx4 c) {
    c = __builtin_amdgcn_mfma_f32_16x16x32_bf16(a, bh, c, 0, 0, 0);
    c = __builtin_amdgcn_mfma_f32_16x16x32_bf16(a, bl, c, 0, 0, 0);
    return c;
}
__device__ __forceinline__ floatx4 mfma3(short8 ah, short8 al, short8 bh, short8 bl, floatx4 c) {
    c = __builtin_amdgcn_mfma_f32_16x16x32_bf16(ah, bh, c, 0, 0, 0);
    c = __builtin_amdgcn_mfma_f32_16x16x32_bf16(al, bh, c, 0, 0, 0);
    c = __builtin_amdgcn_mfma_f32_16x16x32_bf16(ah, bl, c, 0, 0, 0);
    return c;
}

// ---------------- fused prep: weights -> bf16 hi/lo in MFMA B-FRAGMENT ORDER ----------------
// off = (((n>>4)*(K/32) + (k>>5))*4 + ((k>>3)&3))*128 + (n&15)*8 + (k&7)
__global__ void prep_kernel(const float* __restrict__ msg_w1, const float* __restrict__ msg_w2,
                            const float* __restrict__ rbf_w, const float* __restrict__ upd_U,
                            const float* __restrict__ upd_V, const float* __restrict__ upd_w1,
                            const float* __restrict__ upd_w2,
                            short* w1T_h, short* w1T_l, short* w2T_h, short* w2T_l,
                            short* rbfT_h, short* rbfT_l, short* UT_h, short* UT_l,
                            short* VT_h, short* VT_l, short* u1T_h, short* u1T_l,
                            short* u2T_h, short* u2T_l) {
    int m = blockIdx.y;
    int l = blockIdx.x / 384;
    int n = blockIdx.x % 384;
    const float* src; short* dh; short* dl; int K, N;
    switch (m) {
      case 0: src = msg_w1; dh = w1T_h; dl = w1T_l; K = NF;   N = NF; break;
      case 1: src = msg_w2; dh = w2T_h; dl = w2T_l; K = NF;   N = F3; break;
      case 2: src = rbf_w;  dh = rbfT_h;dl = rbfT_l;K = NK;   N = F3; break;
      case 3: src = upd_U;  dh = UT_h;  dl = UT_l;  K = NF;   N = NF; break;
      case 4: src = upd_V;  dh = VT_h;  dl = VT_l;  K = NF;   N = NF; break;
      case 5: src = upd_w1; dh = u1T_h; dl = u1T_l; K = 2*NF; N = NF; break;
      default:src = upd_w2; dh = u2T_h; dl = u2T_l; K = NF;   N = F3; break;
    }
    if (n >= N) return;
    for (int k = threadIdx.x; k < K; k += 64) {
        float x = src[((size_t)l*K + k)*N + n];
        short h = f2bf(x);
        size_t off = (size_t)l*N*K
                   + (size_t)((((n>>4)*(K>>5) + (k>>5))*4 + ((k>>3)&3))*128 + (n&15)*8 + (k&7));
        dh[off] = h;
        dl[off] = f2bf(x - bf2f(h));
    }
}

// ---------------- geometry (once): tkF in MFMA A-FRAGMENT order + weG/dirG ----------------
// tkF index: ((((tile)*4 + ia)*3 + mt)*2 + ks)*512 + lane*8, tile = graph*12+itile
__global__ void __launch_bounds__(384) geom_kernel(const float* __restrict__ pos,
                                                   short* __restrict__ tkF,
                                                   float* __restrict__ weG,
                                                   float* __restrict__ dirG) {
    int raw = blockIdx.x;                 // graph*12 + itile
    int graph = raw / 12, itile = raw % 12;
    int i0l = itile*4, jbase = graph*NA;
    int t = threadIdx.x;
    __shared__ float px[NA], py[NA], pz[NA];
    if (t < NA) {
        px[t] = pos[(jbase+t)*3 + 0];
        py[t] = pos[(jbase+t)*3 + 1];
        pz[t] = pos[(jbase+t)*3 + 2];
    }
    __syncthreads();
    int p = t >> 1, half = t & 1;         // 2 threads per (ii,j), 32 k-bins each
    int ii = p / NA, j = p % NA;
    int il = i0l + ii;
    float dx = px[il] - px[j], dy = py[il] - py[j], dz = pz[il] - pz[j];
    float d2 = dx*dx + dy*dy + dz*dz;
    float dd = sqrtf((j == il) ? 1.0f : d2);       // matches where(eye,1,d2)
    bool valid = (j != il) && (dd < CUTF);
    float we = valid ? 0.5f*(cosf(PI_F * dd / CUTF) + 1.0f) : 0.0f;
    int i = jbase + il;
    if (half == 0) {
        weG[(size_t)i*NA + j] = we;
        float inv = 1.0f / dd;
        dirG[0*(size_t)NN*NA + (size_t)i*NA + j] = dx*inv;
        dirG[1*(size_t)NN*NA + (size_t)i*NA + j] = dy*inv;
        dirG[2*(size_t)NN*NA + (size_t)i*NA + j] = dz*inv;
    }
    int mt = j >> 4, colj = j & 15;
    size_t base = ((((size_t)raw*4 + ii)*3 + mt)*2 + half)*512;
    #pragma unroll
    for (int c = 0; c < 4; ++c) {        // c = quad (k>>3 within 32-chunk)
        short8 h8;
        #pragma unroll
        for (int kk = 0; kk < 8; ++kk) {
            int k = half*32 + c*8 + kk;
            float cen = CUTF * (float)k / 63.0f;
            float df = dd - cen;
            h8[kk] = f2bf(__expf(-GAMMA_F * df * df) * we);   // tk rounded to bf16 anyway
        }
        *(short8*)(tkF + base + (c*16 + colj)*8) = h8;
    }
}

__global__ void zero_kernel(float* __restrict__ p) {
    p[(size_t)blockIdx.x * blockDim.x + threadIdx.x] = 0.f;
}

// ---------------- init + phi(0): s = emb[node_atom], v = 0, phiT(0) ----------------
// 16 nodes/block, 128 thr (2 waves)
__global__ void __launch_bounds__(128) init_phi_kernel(
        const float* __restrict__ emb, const int* __restrict__ node_atom,
        const short* __restrict__ w1T_h, const short* __restrict__ w1T_l,
        const float* __restrict__ b1,
        const short* __restrict__ w2T_h, const short* __restrict__ w2T_l,
        const float* __restrict__ b2,
        float* __restrict__ s, float* __restrict__ v, float* __restrict__ phiT) {
    __shared__ short sH[16*NF], sL[16*NF];
    __shared__ short hH[16*NF], hL[16*NF];
    int t = threadIdx.x;
    int w = t >> 6, lane = t & 63, quad = lane >> 4, col = lane & 15;
    int n0 = blockIdx.x * 16;
    for (int e = t; e < 16*NF; e += 128) {
        int n = e >> 7, f = e & 127;
        int a = node_atom[n0+n];
        float x = emb[(size_t)a*NF + f];
        s[(size_t)(n0+n)*NF + f] = x;
        short h = f2bf(x);
        int ad = n*NF + (((f >> 3) ^ (n & 7)) << 3) + (f & 7);
        sH[ad] = h; sL[ad] = f2bf(x - bf2f(h));
    }
    for (int e = t; e < 16*F3; e += 128) v[(size_t)n0*F3 + e] = 0.f;
    __syncthreads();
    #pragma unroll
    for (int nt = 0; nt < 4; ++nt) {
        int fh = w*64 + nt*16 + col;
        floatx4 acc = (floatx4){0.f,0.f,0.f,0.f};
        #pragma unroll
        for (int ks = 0; ks < 4; ++ks) {
            int ad = col*NF + (((ks*4 + quad) ^ (col & 7)) << 3);
            size_t off = (size_t)((((w*4 + nt)*4 + ks)*4 + quad)*128) + col*8;
            acc = mfma3(*(short8*)&sH[ad], *(short8*)&sL[ad],
                        *(const short8*)(w1T_h + off), *(const short8*)(w1T_l + off), acc);
        }
        float bias = b1[fh];
        #pragma unroll
        for (int r = 0; r < 4; ++r) {
            int n = quad*4 + r;
            float hv = silu_f(acc[r] + bias);
            short h = f2bf(hv);
            int ad = n*NF + (((fh >> 3) ^ (n & 7)) << 3) + (fh & 7);
            hH[ad] = h; hL[ad] = f2bf(hv - bf2f(h));
        }
    }
    __syncthreads();
    #pragma unroll
    for (int nt = 0; nt < 12; ++nt) {
        int tt = w*192 + nt*16 + col;
        floatx4 acc = (floatx4){0.f,0.f,0.f,0.f};
        #pragma unroll
        for (int ks = 0; ks < 4; ++ks) {
            int ad = col*NF + (((ks*4 + quad) ^ (col & 7)) << 3);
            size_t off = (size_t)((((w*12 + nt)*4 + ks)*4 + quad)*128) + col*8;
            acc = mfma3(*(short8*)&hH[ad], *(short8*)&hL[ad],
                        *(const short8*)(w2T_h + off), *(const short8*)(w2T_l + off), acc);
        }
        float bias = b2[tt];
        floatx4 o;
        #pragma unroll
        for (int r = 0; r < 4; ++r) o[r] = acc[r] + bias;
        *(floatx4*)(phiT + (size_t)tt*NN + n0 + quad*4) = o;
    }
}

// ---------------- message: block = (graph, 4-atom tile), 512 thr, BARRIER-FREE ----------------
// tk A-fragments read straight from global (L3-resident); we/dir from global; no LDS.
__global__ void __launch_bounds__(512) message_kernel(
        const float* __restrict__ sIn, const float* __restrict__ vIn,
        const float* __restrict__ phiT, const float* __restrict__ vT,
        const short* __restrict__ tkF, const float* __restrict__ weG,
        const float* __restrict__ dirG,
        const short* __restrict__ rbfT_h, const short* __restrict__ rbfT_l,
        const float* __restrict__ rbf_b_l,
        float* __restrict__ sOut, float* __restrict__ vOut) {
    int raw = blockIdx.x;
    int xcd = raw & 7, idx = raw >> 3;
    int graph = xcd + 8*(idx % 12);
    int itile = idx / 12;
    int i0l = itile*4, jbase = graph*NA;
    int t = threadIdx.x;
    int w = t >> 6, lane = t & 63, quad = lane >> 4, col = lane & 15;
    int f = w*16 + col;
    size_t tkbase = (size_t)(graph*12 + itile)*4*3*2*512;
    float rb0 = rbf_b_l[f], rb1 = rbf_b_l[NF+f], rb2 = rbf_b_l[2*NF+f];
    // hoisted j-side operands (atom-independent): float4 over j = mt*16+quad*4
    floatx4 ph0[3], ph1[3], ph2[3], vj0[3], vj1[3], vj2[3];
    #pragma unroll
    for (int mt = 0; mt < 3; ++mt) {
        int jq = jbase + mt*16 + quad*4;
        ph0[mt] = *(const floatx4*)(phiT + (size_t)f*NN + jq);
        ph1[mt] = *(const floatx4*)(phiT + (size_t)(NF+f)*NN + jq);
        ph2[mt] = *(const floatx4*)(phiT + (size_t)(2*NF+f)*NN + jq);
        vj0[mt] = *(const floatx4*)(vT + (size_t)(0*NF+f)*NN + jq);
        vj1[mt] = *(const floatx4*)(vT + (size_t)(1*NF+f)*NN + jq);
        vj2[mt] = *(const floatx4*)(vT + (size_t)(2*NF+f)*NN + jq);
    }
    for (int ia = 0; ia < 4; ++ia) {
        floatx4 C[3][3];
        #pragma unroll
        for (int g = 0; g < 3; ++g)
            #pragma unroll
            for (int mt = 0; mt < 3; ++mt) C[g][mt] = (floatx4){0.f,0.f,0.f,0.f};
        #pragma unroll
        for (int mt = 0; mt < 3; ++mt) {
            #pragma unroll
            for (int ks = 0; ks < 2; ++ks) {
                short8 a = *(const short8*)(tkF + tkbase + (size_t)(((ia*3 + mt)*2 + ks)*512) + lane*8);
                #pragma unroll
                for (int g = 0; g < 3; ++g) {
                    size_t off = (size_t)((((g*8 + w)*2 + ks)*4 + quad)*128) + col*8;
                    C[g][mt] = mfma2(a, *(const short8*)(rbfT_h + off),
                                        *(const short8*)(rbfT_l + off), C[g][mt]);
                }
            }
        }
        int i = jbase + i0l + ia;
        float accS = 0.f, av0 = 0.f, av1 = 0.f, av2 = 0.f;
        #pragma unroll
        for (int mt = 0; mt < 3; ++mt) {
            int jq = mt*16 + quad*4;
            floatx4 we4 = *(const floatx4*)(weG + (size_t)i*NA + jq);
            floatx4 d0 = *(const floatx4*)(dirG + 0*(size_t)NN*NA + (size_t)i*NA + jq);
            floatx4 d1 = *(const floatx4*)(dirG + 1*(size_t)NN*NA + (size_t)i*NA + jq);
            floatx4 d2 = *(const floatx4*)(dirG + 2*(size_t)NN*NA + (size_t)i*NA + jq);
            #pragma unroll
            for (int r = 0; r < 4; ++r) {
                float Wf0 = fmaf(rb0, we4[r], C[0][mt][r]);
                accS = fmaf(ph0[mt][r], Wf0, accS);
                float Wf1 = fmaf(rb1, we4[r], C[1][mt][r]);
                float x1 = ph1[mt][r] * Wf1;
                av0 = fmaf(x1, vj0[mt][r], av0);
                av1 = fmaf(x1, vj1[mt][r], av1);
                av2 = fmaf(x1, vj2[mt][r], av2);
                float Wf2 = fmaf(rb2, we4[r], C[2][mt][r]);
                float x2 = ph2[mt][r] * Wf2;
                av0 = fmaf(x2, d0[r], av0);
                av1 = fmaf(x2, d1[r], av1);
                av2 = fmaf(x2, d2[r], av2);
            }
        }
        accS += __shfl_xor(accS, 16, 64); accS += __shfl_xor(accS, 32, 64);
        av0 += __shfl_xor(av0, 16, 64);   av0 += __shfl_xor(av0, 32, 64);
        av1 += __shfl_xor(av1, 16, 64);   av1 += __shfl_xor(av1, 32, 64);
        av2 += __shfl_xor(av2, 16, 64);   av2 += __shfl_xor(av2, 32, 64);
        if (quad == 0) {
            sOut[(size_t)i*NF + f]        = sIn[(size_t)i*NF + f]        + accS;
            vOut[(size_t)i*F3 + f]        = vIn[(size_t)i*F3 + f]        + av0;
            vOut[(size_t)i*F3 + NF + f]   = vIn[(size_t)i*F3 + NF + f]   + av1;
            vOut[(size_t)i*F3 + 2*NF + f] = vIn[(size_t)i*F3 + 2*NF + f] + av2;
        }
    }
}

// ---------------- update (+ fused phi for next layer): 16 nodes/block, 256 thr ----------------
__global__ void __launch_bounds__(256) update_phi_kernel(
        const short* __restrict__ UT_h, const short* __restrict__ UT_l,
        const short* __restrict__ VT_h, const short* __restrict__ VT_l,
        const short* __restrict__ u1T_h, const short* __restrict__ u1T_l,
        const float* __restrict__ b1,
        const short* __restrict__ u2T_h, const short* __restrict__ u2T_l,
        const float* __restrict__ b2,
        float* __restrict__ s, float* __restrict__ v, float* __restrict__ vT,
        int doPhi,
        const short* __restrict__ pw1_h, const short* __restrict__ pw1_l,
        const float* __restrict__ pb1,
        const short* __restrict__ pw2_h, const short* __restrict__ pw2_l,
        const float* __restrict__ pb2,
        float* __restrict__ phiT) {
    __shared__ short A1h[48*NF], A1l[48*NF];    // v rows = c*16+n, swizzled
    __shared__ short A2h[16*256], A2l[16*256];  // [s ; Vn]; later reused for s_new (phi A)
    __shared__ short hH[16*NF], hL[16*NF];
    __shared__ float sF[16*132];
    int t = threadIdx.x;
    int w = t >> 6, lane = t & 63, quad = lane >> 4, col = lane & 15;
    int n0 = blockIdx.x * 16;
    int fC = w * 32;
    for (int e = t; e < 16*F3; e += 256) {
        int n = e / F3, cf = e % F3;
        int c = cf >> 7, f = cf & 127;
        float x = v[(size_t)(n0+n)*F3 + cf];
        int row = c*16 + n;
        short h = f2bf(x);
        int ad = row*NF + (((f >> 3) ^ (row & 7)) << 3) + (f & 7);
        A1h[ad] = h; A1l[ad] = f2bf(x - bf2f(h));
    }
    for (int e = t; e < 16*NF; e += 256) {
        int n = e >> 7, f = e & 127;
        float x = s[(size_t)(n0+n)*NF + f];
        sF[n*132 + f] = x;
        short h = f2bf(x);
        int ad = n*256 + (((f >> 3) ^ (n & 7)) << 3) + (f & 7);
        A2h[ad] = h; A2l[ad] = f2bf(x - bf2f(h));
    }
    __syncthreads();
    floatx4 Uacc[3][2], Vacc[3][2];
    #pragma unroll
    for (int mt = 0; mt < 3; ++mt)
        #pragma unroll
        for (int nt = 0; nt < 2; ++nt) { Uacc[mt][nt] = (floatx4){0.f,0.f,0.f,0.f}; Vacc[mt][nt] = (floatx4){0.f,0.f,0.f,0.f}; }
    for (int ks = 0; ks < 4; ++ks) {
        short8 BUh[2], BUl[2], BVh[2], BVl[2];
        #pragma unroll
        for (int nt = 0; nt < 2; ++nt) {
            size_t off = (size_t)((((w*2 + nt)*4 + ks)*4 + quad)*128) + col*8;
            BUh[nt] = *(const short8*)(UT_h + off); BUl[nt] = *(const short8*)(UT_l + off);
            BVh[nt] = *(const short8*)(VT_h + off); BVl[nt] = *(const short8*)(VT_l + off);
        }
        #pragma unroll
        for (int mt = 0; mt < 3; ++mt) {
            int row = mt*16 + col;
            int ad = row*NF + (((ks*4 + quad) ^ (row & 7)) << 3);
            short8 ah = *(short8*)&A1h[ad], al = *(short8*)&A1l[ad];
            #pragma unroll
            for (int nt = 0; nt < 2; ++nt) {
                Uacc[mt][nt] = mfma3(ah, al, BUh[nt], BUl[nt], Uacc[mt][nt]);
                Vacc[mt][nt] = mfma3(ah, al, BVh[nt], BVl[nt], Vacc[mt][nt]);
            }
        }
    }
    #pragma unroll
    for (int nt = 0; nt < 2; ++nt) {
        int f = fC + nt*16 + col;
        #pragma unroll
        for (int r = 0; r < 4; ++r) {
            int n = quad*4 + r;
            float v0 = Vacc[0][nt][r], v1 = Vacc[1][nt][r], v2 = Vacc[2][nt][r];
            float vn = sqrtf(v0*v0 + v1*v1 + v2*v2 + 1e-8f);
            short h = f2bf(vn);
            int ad = n*256 + ((((128 + f) >> 3) ^ (n & 7)) << 3) + (f & 7);
            A2h[ad] = h; A2l[ad] = f2bf(vn - bf2f(h));
        }
    }
    __syncthreads();
    {
        floatx4 H[2];
        #pragma unroll
        for (int nt = 0; nt < 2; ++nt) H[nt] = (floatx4){0.f,0.f,0.f,0.f};
        for (int ks = 0; ks < 8; ++ks) {
            int ad = col*256 + (((ks*4 + quad) ^ (col & 7)) << 3);
            short8 ah = *(short8*)&A2h[ad], al = *(short8*)&A2l[ad];
            #pragma unroll
            for (int nt = 0; nt < 2; ++nt) {
                size_t off = (size_t)((((w*2 + nt)*8 + ks)*4 + quad)*128) + col*8;
                H[nt] = mfma3(ah, al, *(const short8*)(u1T_h + off), *(const short8*)(u1T_l + off), H[nt]);
            }
        }
        #pragma unroll
        for (int nt = 0; nt < 2; ++nt) {
            int f = fC + nt*16 + col;
            float bias = b1[f];
            #pragma unroll
            for (int r = 0; r < 4; ++r) {
                int n = quad*4 + r;
                float hv = silu_f(H[nt][r] + bias);
                short h = f2bf(hv);
                int ad = n*NF + (((f >> 3) ^ (n & 7)) << 3) + (f & 7);
                hH[ad] = h; hL[ad] = f2bf(hv - bf2f(h));
            }
        }
    }
    __syncthreads();
    floatx4 O[3][2];
    #pragma unroll
    for (int gg = 0; gg < 3; ++gg)
        #pragma unroll
        for (int nt = 0; nt < 2; ++nt) O[gg][nt] = (floatx4){0.f,0.f,0.f,0.f};
    for (int ks = 0; ks < 4; ++ks) {
        int ad = col*NF + (((ks*4 + quad) ^ (col & 7)) << 3);
        short8 ah = *(short8*)&hH[ad], al = *(short8*)&hL[ad];
        #pragma unroll
        for (int gg = 0; gg < 3; ++gg)
            #pragma unroll
            for (int nt = 0; nt < 2; ++nt) {
                size_t off = (size_t)((((gg*8 + w*2 + nt)*4 + ks)*4 + quad)*128) + col*8;
                O[gg][nt] = mfma3(ah, al, *(const short8*)(u2T_h + off), *(const short8*)(u2T_l + off), O[gg][nt]);
            }
    }
    __syncthreads();        // A2h/A2l free -> reuse for s_new (phi A operand)
    short* pH = A2h;        // s_new bf16 hi, A1-style layout (n*NF + swz)
    short* pL = A2l;
    #pragma unroll
    for (int nt = 0; nt < 2; ++nt) {
        int f = fC + nt*16 + col;
        float bavv = b2[f], basv = b2[NF + f], bass = b2[2*NF + f];
        #pragma unroll
        for (int r = 0; r < 4; ++r) {
            int n = quad*4 + r;
            float avv = O[0][nt][r] + bavv;
            float asv = O[1][nt][r] + basv;
            float ass = O[2][nt][r] + bass;
            float dot = Uacc[0][nt][r]*Vacc[0][nt][r] + Uacc[1][nt][r]*Vacc[1][nt][r]
                      + Uacc[2][nt][r]*Vacc[2][nt][r];
            float snew = sF[n*132 + f] + asv*dot + ass;
            s[(size_t)(n0+n)*NF + f] = snew;
            short sh = f2bf(snew);
            int adS = n*NF + (((f >> 3) ^ (n & 7)) << 3) + (f & 7);
            pH[adS] = sh; pL[adS] = f2bf(snew - bf2f(sh));
            #pragma unroll
            for (int c = 0; c < 3; ++c) {
                int row = c*16 + n;
                int ad = row*NF + (((f >> 3) ^ (row & 7)) << 3) + (f & 7);
                float vold = bf2f(A1h[ad]) + bf2f(A1l[ad]);
                float vnew = vold + avv*Uacc[c][nt][r];
                v[(size_t)(n0+n)*F3 + c*NF + f] = vnew;
                vT[(size_t)(c*NF + f)*NN + n0 + n] = vnew;
            }
        }
    }
    if (!doPhi) return;
    __syncthreads();
    // phi GEMM1: 4 waves x 2 tiles (fh = w*32 + nt*16 + col)
    #pragma unroll
    for (int nt = 0; nt < 2; ++nt) {
        int fh = w*32 + nt*16 + col;
        floatx4 acc = (floatx4){0.f,0.f,0.f,0.f};
        #pragma unroll
        for (int ks = 0; ks < 4; ++ks) {
            int ad = col*NF + (((ks*4 + quad) ^ (col & 7)) << 3);
            size_t off = (size_t)((((w*2 + nt)*4 + ks)*4 + quad)*128) + col*8;
            acc = mfma3(*(short8*)&pH[ad], *(short8*)&pL[ad],
                        *(const short8*)(pw1_h + off), *(const short8*)(pw1_l + off), acc);
        }
        float bias = pb1[fh];
        #pragma unroll
        for (int r = 0; r < 4; ++r) {
            int n = quad*4 + r;
            float hv = silu_f(acc[r] + bias);
            short h = f2bf(hv);
            int ad = n*NF + (((fh >> 3) ^ (n & 7)) << 3) + (fh & 7);
            hH[ad] = h; hL[ad] = f2bf(hv - bf2f(h));
        }
    }
    __syncthreads();
    // phi GEMM2: 4 waves x 6 tiles (tt = (w*6+nt)*16 + col)
    #pragma unroll
    for (int nt = 0; nt < 6; ++nt) {
        int tt = (w*6 + nt)*16 + col;
        floatx4 acc = (floatx4){0.f,0.f,0.f,0.f};
        #pragma unroll
        for (int ks = 0; ks < 4; ++ks) {
            int ad = col*NF + (((ks*4 + quad) ^ (col & 7)) << 3);
            size_t off = (size_t)((((w*6 + nt)*4 + ks)*4 + quad)*128) + col*8;
            acc = mfma3(*(short8*)&hH[ad], *(short8*)&hL[ad],
                        *(const short8*)(pw2_h + off), *(const short8*)(pw2_l + off), acc);
        }
        float bias = pb2[tt];
        floatx4 o;
        #pragma unroll
        for (int r = 0; r < 4; ++r) o[r] = acc[r] + bias;
        *(floatx4*)(phiT + (size_t)tt*NN + n0 + quad*4) = o;
    }
}

// ---------------- output head ----------------
__global__ void zero_out_kernel(float* __restrict__ out) {
    out[threadIdx.x] = 0.f;
}

__global__ void out_kernel(const float* __restrict__ s,
                           const float* __restrict__ w1, const float* __restrict__ b1,
                           const float* __restrict__ w2, const float* __restrict__ b2,
                           float* __restrict__ out) {
    int n = blockIdx.x;
    int f = threadIdx.x;
    __shared__ float sh[NF];
    __shared__ float r2[2];
    sh[f] = s[n*NF + f];
    __syncthreads();
    float acc = b1[f];
    for (int g = 0; g < NF; ++g) acc = fmaf(sh[g], w1[g*NF + f], acc);
    float p = silu_f(acc) * w2[f];
    #pragma unroll
    for (int off = 32; off > 0; off >>= 1) p += __shfl_down(p, off, 64);
    if ((f & 63) == 0) r2[f >> 6] = p;
    __syncthreads();
    if (f == 0) atomicAdd(&out[n / NA], r2[0] + r2[1] + b2[0]);
}

extern "C" void kernel_launch(void* const* d_in, const int* in_sizes, int n_in,
                              void* d_out, int out_size, void* d_ws, size_t ws_size,
                              hipStream_t stream) {
    (void)in_sizes; (void)n_in; (void)out_size; (void)ws_size;
    const float* pos      = (const float*)d_in[1];
    const int*   node_atom= (const int*)  d_in[3];
    const float* emb      = (const float*)d_in[4];
    const float* msg_w1   = (const float*)d_in[5];
    const float* msg_b1   = (const float*)d_in[6];
    const float* msg_w2   = (const float*)d_in[7];
    const float* msg_b2   = (const float*)d_in[8];
    const float* rbf_w    = (const float*)d_in[9];
    const float* rbf_b    = (const float*)d_in[10];
    const float* upd_U    = (const float*)d_in[11];
    const float* upd_V    = (const float*)d_in[12];
    const float* upd_w1   = (const float*)d_in[13];
    const float* upd_b1   = (const float*)d_in[14];
    const float* upd_w2   = (const float*)d_in[15];
    const float* upd_b2   = (const float*)d_in[16];
    const float* out_w1   = (const float*)d_in[17];
    const float* out_b1   = (const float*)d_in[18];
    const float* out_w2   = (const float*)d_in[19];
    const float* out_b2   = (const float*)d_in[20];
    float* out = (float*)d_out;

    float* ws   = (float*)d_ws;
    float* sA   = ws; ws += (size_t)NN*NF;
    float* sB   = ws; ws += (size_t)NN*NF;
    float* vA   = ws; ws += (size_t)NN*F3;
    float* vB   = ws; ws += (size_t)NN*F3;
    float* phiT = ws; ws += (size_t)F3*NN;
    float* vT   = ws; ws += (size_t)F3*NN;
    float* weG  = ws; ws += (size_t)NN*NA;
    float* dirG = ws; ws += (size_t)3*NN*NA;
    short* sp    = (short*)ws;
    short* tkF   = sp; sp += (size_t)NB*12*4*3*2*512;
    short* w1T_h = sp; sp += (size_t)NL*NF*NF;
    short* w1T_l = sp; sp += (size_t)NL*NF*NF;
    short* w2T_h = sp; sp += (size_t)NL*F3*NF;
    short* w2T_l = sp; sp += (size_t)NL*F3*NF;
    short* rbfT_h= sp; sp += (size_t)NL*F3*NK;
    short* rbfT_l= sp; sp += (size_t)NL*F3*NK;
    short* UT_h  = sp; sp += (size_t)NL*NF*NF;
    short* UT_l  = sp; sp += (size_t)NL*NF*NF;
    short* VT_h  = sp; sp += (size_t)NL*NF*NF;
    short* VT_l  = sp; sp += (size_t)NL*NF*NF;
    short* u1T_h = sp; sp += (size_t)NL*NF*2*NF;
    short* u1T_l = sp; sp += (size_t)NL*NF*2*NF;
    short* u2T_h = sp; sp += (size_t)NL*F3*NF;
    short* u2T_l = sp; sp += (size_t)NL*F3*NF;

    prep_kernel<<<dim3(NL*384, 7), 64, 0, stream>>>(msg_w1, msg_w2, rbf_w, upd_U, upd_V, upd_w1, upd_w2,
                                                    w1T_h, w1T_l, w2T_h, w2T_l, rbfT_h, rbfT_l,
                                                    UT_h, UT_l, VT_h, VT_l, u1T_h, u1T_l, u2T_h, u2T_l);
    geom_kernel<<<NB*12, 384, 0, stream>>>(pos, tkF, weG, dirG);
    zero_kernel<<<(F3*NN)/256, 256, 0, stream>>>(vT);
    init_phi_kernel<<<NN/16, 128, 0, stream>>>(emb, node_atom,
                                               w1T_h, w1T_l, msg_b1, w2T_h, w2T_l, msg_b2,
                                               sA, vA, phiT);

    float* sC = sA; float* vC = vA; float* sN = sB; float* vN = vB;
    for (int l = 0; l < NL; ++l) {
        message_kernel<<<NB*12, 512, 0, stream>>>(sC, vC, phiT, vT,
                                                  tkF, weG, dirG,
                                                  rbfT_h + (size_t)l*F3*NK, rbfT_l + (size_t)l*F3*NK,
                                                  rbf_b + (size_t)l*F3, sN, vN);
        int lp = (l + 1 < NL) ? (l + 1) : 0;
        update_phi_kernel<<<NN/16, 256, 0, stream>>>(
            UT_h + (size_t)l*NF*NF, UT_l + (size_t)l*NF*NF,
            VT_h + (size_t)l*NF*NF, VT_l + (size_t)l*NF*NF,
            u1T_h + (size_t)l*NF*2*NF, u1T_l + (size_t)l*NF*2*NF,
            upd_b1 + (size_t)l*NF,
            u2T_h + (size_t)l*F3*NF, u2T_l + (size_t)l*F3*NF,
            upd_b2 + (size_t)l*F3, sN, vN, vT,
            (l + 1 < NL) ? 1 : 0,
            w1T_h + (size_t)lp*NF*NF, w1T_l + (size_t)lp*NF*NF, msg_b1 + (size_t)lp*NF,
            w2T_h + (size_t)lp*F3*NF, w2T_l + (size_t)lp*F3*NF, msg_b2 + (size_t)lp*F3,
            phiT);
        float* tp;
        tp = sC; sC = sN; sN = tp;
        tp = vC; vC = vN; vN = tp;
    }
    zero_out_kernel<<<1, NB, 0, stream>>>(out);
    out_kernel<<<NN, NF, 0, stream>>>(sC, out_w1, out_b1, out_w2, out_b2, out);
}

// Round 8
// 751.633 us; speedup vs baseline: 2.0728x; 1.0508x over previous
//
#include <hip/hip_runtime.h>
#include <math.h>

#define NB 96
#define NA 48
#define NF 128
#define NK 64
#define NL 6
#define NN (NB*NA)     // 4608 nodes
#define F3 (3*NF)      // 384
#define CUTF 5.0f
#define GAMMA_F ((float)(1.0 / (0.006103515625 + 1e-9)))
#define PI_F 3.14159265358979323846f

typedef __attribute__((ext_vector_type(8))) short short8;
typedef __attribute__((ext_vector_type(4))) float floatx4;

__device__ __forceinline__ float silu_f(float x) { return x / (1.0f + expf(-x)); }

__device__ __forceinline__ short f2bf(float x) {
    unsigned u = __builtin_bit_cast(unsigned, x);
    unsigned r = (u + 0x7fffu + ((u >> 16) & 1u)) >> 16;   // RNE
    return (short)r;
}
__device__ __forceinline__ float bf2f(short h) {
    unsigned u = ((unsigned)(unsigned short)h) << 16;
    return __builtin_bit_cast(float, u);
}
__device__ __forceinline__ floatx4 mfma1(short8 a, short8 b, floatx4 c) {
    return __builtin_amdgcn_mfma_f32_16x16x32_bf16(a, b, c, 0, 0, 0);
}
__device__ __forceinline__ floatx4 mfma3(short8 ah, short8 al, short8 bh, short8 bl, floatx4 c) {
    c = __builtin_amdgcn_mfma_f32_16x16x32_bf16(ah, bh, c, 0, 0, 0);
    c = __builtin_amdgcn_mfma_f32_16x16x32_bf16(al, bh, c, 0, 0, 0);
    c = __builtin_amdgcn_mfma_f32_16x16x32_bf16(ah, bl, c, 0, 0, 0);
    return c;
}

// ---------------- fused prep: weights -> bf16 hi/lo in MFMA B-FRAGMENT ORDER ----------------
// off = (((n>>4)*(K/32) + (k>>5))*4 + ((k>>3)&3))*128 + (n&15)*8 + (k&7)
__global__ void prep_kernel(const float* __restrict__ msg_w1, const float* __restrict__ msg_w2,
                            const float* __restrict__ rbf_w, const float* __restrict__ upd_U,
                            const float* __restrict__ upd_V, const float* __restrict__ upd_w1,
                            const float* __restrict__ upd_w2,
                            short* w1T_h, short* w1T_l, short* w2T_h, short* w2T_l,
                            short* rbfT_h, short* rbfT_l, short* UT_h, short* UT_l,
                            short* VT_h, short* VT_l, short* u1T_h, short* u1T_l,
                            short* u2T_h, short* u2T_l) {
    int m = blockIdx.y;
    int l = blockIdx.x / 384;
    int n = blockIdx.x % 384;
    const float* src; short* dh; short* dl; int K, N;
    switch (m) {
      case 0: src = msg_w1; dh = w1T_h; dl = w1T_l; K = NF;   N = NF; break;
      case 1: src = msg_w2; dh = w2T_h; dl = w2T_l; K = NF;   N = F3; break;
      case 2: src = rbf_w;  dh = rbfT_h;dl = rbfT_l;K = NK;   N = F3; break;
      case 3: src = upd_U;  dh = UT_h;  dl = UT_l;  K = NF;   N = NF; break;
      case 4: src = upd_V;  dh = VT_h;  dl = VT_l;  K = NF;   N = NF; break;
      case 5: src = upd_w1; dh = u1T_h; dl = u1T_l; K = 2*NF; N = NF; break;
      default:src = upd_w2; dh = u2T_h; dl = u2T_l; K = NF;   N = F3; break;
    }
    if (n >= N) return;
    for (int k = threadIdx.x; k < K; k += 64) {
        float x = src[((size_t)l*K + k)*N + n];
        short h = f2bf(x);
        size_t off = (size_t)l*N*K
                   + (size_t)((((n>>4)*(K>>5) + (k>>5))*4 + ((k>>3)&3))*128 + (n&15)*8 + (k&7));
        dh[off] = h;
        dl[off] = f2bf(x - bf2f(h));
    }
}

// ---------------- geometry (once): tkF in MFMA A-FRAGMENT order + weG/dirG ----------------
__global__ void __launch_bounds__(384) geom_kernel(const float* __restrict__ pos,
                                                   short* __restrict__ tkF,
                                                   float* __restrict__ weG,
                                                   float* __restrict__ dirG) {
    int raw = blockIdx.x;                 // graph*12 + itile
    int graph = raw / 12, itile = raw % 12;
    int i0l = itile*4, jbase = graph*NA;
    int t = threadIdx.x;
    __shared__ float px[NA], py[NA], pz[NA];
    if (t < NA) {
        px[t] = pos[(jbase+t)*3 + 0];
        py[t] = pos[(jbase+t)*3 + 1];
        pz[t] = pos[(jbase+t)*3 + 2];
    }
    __syncthreads();
    int p = t >> 1, half = t & 1;         // 2 threads per (ii,j), 32 k-bins each
    int ii = p / NA, j = p % NA;
    int il = i0l + ii;
    float dx = px[il] - px[j], dy = py[il] - py[j], dz = pz[il] - pz[j];
    float d2 = dx*dx + dy*dy + dz*dz;
    float dd = sqrtf((j == il) ? 1.0f : d2);       // matches where(eye,1,d2)
    bool valid = (j != il) && (dd < CUTF);
    float we = valid ? 0.5f*(cosf(PI_F * dd / CUTF) + 1.0f) : 0.0f;
    int i = jbase + il;
    if (half == 0) {
        weG[(size_t)i*NA + j] = we;
        float inv = 1.0f / dd;
        dirG[0*(size_t)NN*NA + (size_t)i*NA + j] = dx*inv;
        dirG[1*(size_t)NN*NA + (size_t)i*NA + j] = dy*inv;
        dirG[2*(size_t)NN*NA + (size_t)i*NA + j] = dz*inv;
    }
    int mt = j >> 4, colj = j & 15;
    size_t base = ((((size_t)raw*4 + ii)*3 + mt)*2 + half)*512;
    #pragma unroll
    for (int c = 0; c < 4; ++c) {        // c = quad (k>>3 within 32-chunk)
        short8 h8;
        #pragma unroll
        for (int kk = 0; kk < 8; ++kk) {
            int k = half*32 + c*8 + kk;
            float cen = CUTF * (float)k / 63.0f;
            float df = dd - cen;
            h8[kk] = f2bf(__expf(-GAMMA_F * df * df) * we);
        }
        *(short8*)(tkF + base + (c*16 + colj)*8) = h8;
    }
}

__global__ void zero_kernel(float* __restrict__ p) {
    p[(size_t)blockIdx.x * blockDim.x + threadIdx.x] = 0.f;
}

// ---------------- init + phi(0) ----------------
__global__ void __launch_bounds__(128) init_phi_kernel(
        const float* __restrict__ emb, const int* __restrict__ node_atom,
        const short* __restrict__ w1T_h, const short* __restrict__ w1T_l,
        const float* __restrict__ b1,
        const short* __restrict__ w2T_h, const short* __restrict__ w2T_l,
        const float* __restrict__ b2,
        float* __restrict__ s, float* __restrict__ v, float* __restrict__ phiT) {
    __shared__ short sH[16*NF], sL[16*NF];
    __shared__ short hH[16*NF], hL[16*NF];
    int t = threadIdx.x;
    int w = t >> 6, lane = t & 63, quad = lane >> 4, col = lane & 15;
    int n0 = blockIdx.x * 16;
    for (int e = t; e < 16*NF; e += 128) {
        int n = e >> 7, f = e & 127;
        int a = node_atom[n0+n];
        float x = emb[(size_t)a*NF + f];
        s[(size_t)(n0+n)*NF + f] = x;
        short h = f2bf(x);
        int ad = n*NF + (((f >> 3) ^ (n & 7)) << 3) + (f & 7);
        sH[ad] = h; sL[ad] = f2bf(x - bf2f(h));
    }
    for (int e = t; e < 16*F3; e += 128) v[(size_t)n0*F3 + e] = 0.f;
    __syncthreads();
    #pragma unroll
    for (int nt = 0; nt < 4; ++nt) {
        int fh = w*64 + nt*16 + col;
        floatx4 acc = (floatx4){0.f,0.f,0.f,0.f};
        #pragma unroll
        for (int ks = 0; ks < 4; ++ks) {
            int ad = col*NF + (((ks*4 + quad) ^ (col & 7)) << 3);
            size_t off = (size_t)((((w*4 + nt)*4 + ks)*4 + quad)*128) + col*8;
            acc = mfma3(*(short8*)&sH[ad], *(short8*)&sL[ad],
                        *(const short8*)(w1T_h + off), *(const short8*)(w1T_l + off), acc);
        }
        float bias = b1[fh];
        #pragma unroll
        for (int r = 0; r < 4; ++r) {
            int n = quad*4 + r;
            float hv = silu_f(acc[r] + bias);
            short h = f2bf(hv);
            int ad = n*NF + (((fh >> 3) ^ (n & 7)) << 3) + (fh & 7);
            hH[ad] = h; hL[ad] = f2bf(hv - bf2f(h));
        }
    }
    __syncthreads();
    #pragma unroll
    for (int nt = 0; nt < 12; ++nt) {
        int tt = w*192 + nt*16 + col;
        floatx4 acc = (floatx4){0.f,0.f,0.f,0.f};
        #pragma unroll
        for (int ks = 0; ks < 4; ++ks) {
            int ad = col*NF + (((ks*4 + quad) ^ (col & 7)) << 3);
            size_t off = (size_t)((((w*12 + nt)*4 + ks)*4 + quad)*128) + col*8;
            acc = mfma3(*(short8*)&hH[ad], *(short8*)&hL[ad],
                        *(const short8*)(w2T_h + off), *(const short8*)(w2T_l + off), acc);
        }
        float bias = b2[tt];
        floatx4 o;
        #pragma unroll
        for (int r = 0; r < 4; ++r) o[r] = acc[r] + bias;
        *(floatx4*)(phiT + (size_t)tt*NN + n0 + quad*4) = o;
    }
}

// ---------------- message: block = (graph, 4-atom tile), 512 thr, barrier-free ----------------
// rbf B-fragments hi-only, HOISTED to registers (6 short8). Inner loop: 6 tkF loads + 18 MFMA.
__global__ void __launch_bounds__(512) message_kernel(
        const float* __restrict__ sIn, const float* __restrict__ vIn,
        const float* __restrict__ phiT, const float* __restrict__ vT,
        const short* __restrict__ tkF, const float* __restrict__ weG,
        const float* __restrict__ dirG,
        const short* __restrict__ rbfT_h,
        const float* __restrict__ rbf_b_l,
        float* __restrict__ sOut, float* __restrict__ vOut) {
    int raw = blockIdx.x;
    int xcd = raw & 7, idx = raw >> 3;
    int graph = xcd + 8*(idx % 12);
    int itile = idx / 12;
    int i0l = itile*4, jbase = graph*NA;
    int t = threadIdx.x;
    int w = t >> 6, lane = t & 63, quad = lane >> 4, col = lane & 15;
    int f = w*16 + col;
    size_t tkbase = (size_t)(graph*12 + itile)*4*3*2*512;
    float rb0 = rbf_b_l[f], rb1 = rbf_b_l[NF+f], rb2 = rbf_b_l[2*NF+f];
    // hoisted B fragments (wave-invariant across ia): [g][ks]
    short8 B[3][2];
    #pragma unroll
    for (int g = 0; g < 3; ++g)
        #pragma unroll
        for (int ks = 0; ks < 2; ++ks)
            B[g][ks] = *(const short8*)(rbfT_h + (size_t)((((g*8 + w)*2 + ks)*4 + quad)*128) + col*8);
    // hoisted j-side operands (atom-independent): float4 over j = mt*16+quad*4
    floatx4 ph0[3], ph1[3], ph2[3], vj0[3], vj1[3], vj2[3];
    #pragma unroll
    for (int mt = 0; mt < 3; ++mt) {
        int jq = jbase + mt*16 + quad*4;
        ph0[mt] = *(const floatx4*)(phiT + (size_t)f*NN + jq);
        ph1[mt] = *(const floatx4*)(phiT + (size_t)(NF+f)*NN + jq);
        ph2[mt] = *(const floatx4*)(phiT + (size_t)(2*NF+f)*NN + jq);
        vj0[mt] = *(const floatx4*)(vT + (size_t)(0*NF+f)*NN + jq);
        vj1[mt] = *(const floatx4*)(vT + (size_t)(1*NF+f)*NN + jq);
        vj2[mt] = *(const floatx4*)(vT + (size_t)(2*NF+f)*NN + jq);
    }
    for (int ia = 0; ia < 4; ++ia) {
        floatx4 C[3][3];
        #pragma unroll
        for (int g = 0; g < 3; ++g)
            #pragma unroll
            for (int mt = 0; mt < 3; ++mt) C[g][mt] = (floatx4){0.f,0.f,0.f,0.f};
        #pragma unroll
        for (int mt = 0; mt < 3; ++mt) {
            #pragma unroll
            for (int ks = 0; ks < 2; ++ks) {
                short8 a = *(const short8*)(tkF + tkbase + (size_t)(((ia*3 + mt)*2 + ks)*512) + lane*8);
                #pragma unroll
                for (int g = 0; g < 3; ++g)
                    C[g][mt] = mfma1(a, B[g][ks], C[g][mt]);
            }
        }
        int i = jbase + i0l + ia;
        float accS = 0.f, av0 = 0.f, av1 = 0.f, av2 = 0.f;
        #pragma unroll
        for (int mt = 0; mt < 3; ++mt) {
            int jq = mt*16 + quad*4;
            floatx4 we4 = *(const floatx4*)(weG + (size_t)i*NA + jq);
            floatx4 d0 = *(const floatx4*)(dirG + 0*(size_t)NN*NA + (size_t)i*NA + jq);
            floatx4 d1 = *(const floatx4*)(dirG + 1*(size_t)NN*NA + (size_t)i*NA + jq);
            floatx4 d2 = *(const floatx4*)(dirG + 2*(size_t)NN*NA + (size_t)i*NA + jq);
            #pragma unroll
            for (int r = 0; r < 4; ++r) {
                float Wf0 = fmaf(rb0, we4[r], C[0][mt][r]);
                accS = fmaf(ph0[mt][r], Wf0, accS);
                float Wf1 = fmaf(rb1, we4[r], C[1][mt][r]);
                float x1 = ph1[mt][r] * Wf1;
                av0 = fmaf(x1, vj0[mt][r], av0);
                av1 = fmaf(x1, vj1[mt][r], av1);
                av2 = fmaf(x1, vj2[mt][r], av2);
                float Wf2 = fmaf(rb2, we4[r], C[2][mt][r]);
                float x2 = ph2[mt][r] * Wf2;
                av0 = fmaf(x2, d0[r], av0);
                av1 = fmaf(x2, d1[r], av1);
                av2 = fmaf(x2, d2[r], av2);
            }
        }
        accS += __shfl_xor(accS, 16, 64); accS += __shfl_xor(accS, 32, 64);
        av0 += __shfl_xor(av0, 16, 64);   av0 += __shfl_xor(av0, 32, 64);
        av1 += __shfl_xor(av1, 16, 64);   av1 += __shfl_xor(av1, 32, 64);
        av2 += __shfl_xor(av2, 16, 64);   av2 += __shfl_xor(av2, 32, 64);
        if (quad == 0) {
            sOut[(size_t)i*NF + f]        = sIn[(size_t)i*NF + f]        + accS;
            vOut[(size_t)i*F3 + f]        = vIn[(size_t)i*F3 + f]        + av0;
            vOut[(size_t)i*F3 + NF + f]   = vIn[(size_t)i*F3 + NF + f]   + av1;
            vOut[(size_t)i*F3 + 2*NF + f] = vIn[(size_t)i*F3 + 2*NF + f] + av2;
        }
    }
}

// ---------------- update (+ fused phi): 16 nodes/block, 512 thr = 8 waves (1 tile each) ----------------
__global__ void __launch_bounds__(512) update_phi_kernel(
        const short* __restrict__ UT_h, const short* __restrict__ UT_l,
        const short* __restrict__ VT_h, const short* __restrict__ VT_l,
        const short* __restrict__ u1T_h, const short* __restrict__ u1T_l,
        const float* __restrict__ b1,
        const short* __restrict__ u2T_h, const short* __restrict__ u2T_l,
        const float* __restrict__ b2,
        float* __restrict__ s, float* __restrict__ v, float* __restrict__ vT,
        int doPhi,
        const short* __restrict__ pw1_h, const short* __restrict__ pw1_l,
        const float* __restrict__ pb1,
        const short* __restrict__ pw2_h, const short* __restrict__ pw2_l,
        const float* __restrict__ pb2,
        float* __restrict__ phiT) {
    __shared__ short A1h[48*NF], A1l[48*NF];    // v rows = c*16+n, swizzled
    __shared__ short A2h[16*256], A2l[16*256];  // [s ; Vn]; later reused for s_new
    __shared__ short hH[16*NF], hL[16*NF];
    __shared__ float sF[16*132];
    int t = threadIdx.x;
    int w = t >> 6, lane = t & 63, quad = lane >> 4, col = lane & 15;
    int n0 = blockIdx.x * 16;
    int f = w*16 + col;                 // this wave's 16-feature tile
    for (int e = t; e < 16*F3; e += 512) {
        int n = e / F3, cf = e % F3;
        int c = cf >> 7, ff = cf & 127;
        float x = v[(size_t)(n0+n)*F3 + cf];
        int row = c*16 + n;
        short h = f2bf(x);
        int ad = row*NF + (((ff >> 3) ^ (row & 7)) << 3) + (ff & 7);
        A1h[ad] = h; A1l[ad] = f2bf(x - bf2f(h));
    }
    for (int e = t; e < 16*NF; e += 512) {
        int n = e >> 7, ff = e & 127;
        float x = s[(size_t)(n0+n)*NF + ff];
        sF[n*132 + ff] = x;
        short h = f2bf(x);
        int ad = n*256 + (((ff >> 3) ^ (n & 7)) << 3) + (ff & 7);
        A2h[ad] = h; A2l[ad] = f2bf(x - bf2f(h));
    }
    __syncthreads();
    floatx4 Uacc[3], Vacc[3];
    #pragma unroll
    for (int mt = 0; mt < 3; ++mt) { Uacc[mt] = (floatx4){0.f,0.f,0.f,0.f}; Vacc[mt] = (floatx4){0.f,0.f,0.f,0.f}; }
    #pragma unroll
    for (int ks = 0; ks < 4; ++ks) {
        size_t off = (size_t)(((w*4 + ks)*4 + quad)*128) + col*8;
        short8 BUh = *(const short8*)(UT_h + off), BUl = *(const short8*)(UT_l + off);
        short8 BVh = *(const short8*)(VT_h + off), BVl = *(const short8*)(VT_l + off);
        #pragma unroll
        for (int mt = 0; mt < 3; ++mt) {
            int row = mt*16 + col;
            int ad = row*NF + (((ks*4 + quad) ^ (row & 7)) << 3);
            short8 ah = *(short8*)&A1h[ad], al = *(short8*)&A1l[ad];
            Uacc[mt] = mfma3(ah, al, BUh, BUl, Uacc[mt]);
            Vacc[mt] = mfma3(ah, al, BVh, BVl, Vacc[mt]);
        }
    }
    #pragma unroll
    for (int r = 0; r < 4; ++r) {
        int n = quad*4 + r;
        float v0 = Vacc[0][r], v1 = Vacc[1][r], v2 = Vacc[2][r];
        float vn = sqrtf(v0*v0 + v1*v1 + v2*v2 + 1e-8f);
        short h = f2bf(vn);
        int ad = n*256 + ((((128 + f) >> 3) ^ (n & 7)) << 3) + (f & 7);
        A2h[ad] = h; A2l[ad] = f2bf(vn - bf2f(h));
    }
    __syncthreads();
    {
        floatx4 H = (floatx4){0.f,0.f,0.f,0.f};
        #pragma unroll
        for (int ks = 0; ks < 8; ++ks) {
            int ad = col*256 + (((ks*4 + quad) ^ (col & 7)) << 3);
            short8 ah = *(short8*)&A2h[ad], al = *(short8*)&A2l[ad];
            size_t off = (size_t)(((w*8 + ks)*4 + quad)*128) + col*8;
            H = mfma3(ah, al, *(const short8*)(u1T_h + off), *(const short8*)(u1T_l + off), H);
        }
        float bias = b1[f];
        #pragma unroll
        for (int r = 0; r < 4; ++r) {
            int n = quad*4 + r;
            float hv = silu_f(H[r] + bias);
            short h = f2bf(hv);
            int ad = n*NF + (((f >> 3) ^ (n & 7)) << 3) + (f & 7);
            hH[ad] = h; hL[ad] = f2bf(hv - bf2f(h));
        }
    }
    __syncthreads();
    floatx4 O[3];
    #pragma unroll
    for (int gg = 0; gg < 3; ++gg) O[gg] = (floatx4){0.f,0.f,0.f,0.f};
    #pragma unroll
    for (int ks = 0; ks < 4; ++ks) {
        int ad = col*NF + (((ks*4 + quad) ^ (col & 7)) << 3);
        short8 ah = *(short8*)&hH[ad], al = *(short8*)&hL[ad];
        #pragma unroll
        for (int gg = 0; gg < 3; ++gg) {
            size_t off = (size_t)((((gg*8 + w)*4 + ks)*4 + quad)*128) + col*8;
            O[gg] = mfma3(ah, al, *(const short8*)(u2T_h + off), *(const short8*)(u2T_l + off), O[gg]);
        }
    }
    __syncthreads();        // A2h/A2l free -> reuse for s_new (phi A operand)
    short* pH = A2h;
    short* pL = A2l;
    {
        float bavv = b2[f], basv = b2[NF + f], bass = b2[2*NF + f];
        #pragma unroll
        for (int r = 0; r < 4; ++r) {
            int n = quad*4 + r;
            float avv = O[0][r] + bavv;
            float asv = O[1][r] + basv;
            float ass = O[2][r] + bass;
            float dot = Uacc[0][r]*Vacc[0][r] + Uacc[1][r]*Vacc[1][r] + Uacc[2][r]*Vacc[2][r];
            float snew = sF[n*132 + f] + asv*dot + ass;
            s[(size_t)(n0+n)*NF + f] = snew;
            short sh = f2bf(snew);
            int adS = n*NF + (((f >> 3) ^ (n & 7)) << 3) + (f & 7);
            pH[adS] = sh; pL[adS] = f2bf(snew - bf2f(sh));
            #pragma unroll
            for (int c = 0; c < 3; ++c) {
                int row = c*16 + n;
                int ad = row*NF + (((f >> 3) ^ (row & 7)) << 3) + (f & 7);
                float vold = bf2f(A1h[ad]) + bf2f(A1l[ad]);
                float vnew = vold + avv*Uacc[c][r];
                v[(size_t)(n0+n)*F3 + c*NF + f] = vnew;
                vT[(size_t)(c*NF + f)*NN + n0 + n] = vnew;
            }
        }
    }
    if (!doPhi) return;
    __syncthreads();
    // phi GEMM1: wave w -> feature tile w (fh = w*16+col)
    {
        floatx4 acc = (floatx4){0.f,0.f,0.f,0.f};
        #pragma unroll
        for (int ks = 0; ks < 4; ++ks) {
            int ad = col*NF + (((ks*4 + quad) ^ (col & 7)) << 3);
            size_t off = (size_t)(((w*4 + ks)*4 + quad)*128) + col*8;
            acc = mfma3(*(short8*)&pH[ad], *(short8*)&pL[ad],
                        *(const short8*)(pw1_h + off), *(const short8*)(pw1_l + off), acc);
        }
        float bias = pb1[f];
        #pragma unroll
        for (int r = 0; r < 4; ++r) {
            int n = quad*4 + r;
            float hv = silu_f(acc[r] + bias);
            short h = f2bf(hv);
            int ad = n*NF + (((f >> 3) ^ (n & 7)) << 3) + (f & 7);
            hH[ad] = h; hL[ad] = f2bf(hv - bf2f(h));
        }
    }
    __syncthreads();
    // phi GEMM2: 8 waves x 3 tiles (tt = (w*3+nt)*16 + col)
    #pragma unroll
    for (int nt = 0; nt < 3; ++nt) {
        int tt = (w*3 + nt)*16 + col;
        floatx4 acc = (floatx4){0.f,0.f,0.f,0.f};
        #pragma unroll
        for (int ks = 0; ks < 4; ++ks) {
            int ad = col*NF + (((ks*4 + quad) ^ (col & 7)) << 3);
            size_t off = (size_t)((((w*3 + nt)*4 + ks)*4 + quad)*128) + col*8;
            acc = mfma3(*(short8*)&hH[ad], *(short8*)&hL[ad],
                        *(const short8*)(pw2_h + off), *(const short8*)(pw2_l + off), acc);
        }
        float bias = pb2[tt];
        floatx4 o;
        #pragma unroll
        for (int r = 0; r < 4; ++r) o[r] = acc[r] + bias;
        *(floatx4*)(phiT + (size_t)tt*NN + n0 + quad*4) = o;
    }
}

// ---------------- output head ----------------
__global__ void zero_out_kernel(float* __restrict__ out) {
    out[threadIdx.x] = 0.f;
}

__global__ void out_kernel(const float* __restrict__ s,
                           const float* __restrict__ w1, const float* __restrict__ b1,
                           const float* __restrict__ w2, const float* __restrict__ b2,
                           float* __restrict__ out) {
    int n = blockIdx.x;
    int f = threadIdx.x;
    __shared__ float sh[NF];
    __shared__ float r2[2];
    sh[f] = s[n*NF + f];
    __syncthreads();
    float acc = b1[f];
    for (int g = 0; g < NF; ++g) acc = fmaf(sh[g], w1[g*NF + f], acc);
    float p = silu_f(acc) * w2[f];
    #pragma unroll
    for (int off = 32; off > 0; off >>= 1) p += __shfl_down(p, off, 64);
    if ((f & 63) == 0) r2[f >> 6] = p;
    __syncthreads();
    if (f == 0) atomicAdd(&out[n / NA], r2[0] + r2[1] + b2[0]);
}

extern "C" void kernel_launch(void* const* d_in, const int* in_sizes, int n_in,
                              void* d_out, int out_size, void* d_ws, size_t ws_size,
                              hipStream_t stream) {
    (void)in_sizes; (void)n_in; (void)out_size; (void)ws_size;
    const float* pos      = (const float*)d_in[1];
    const int*   node_atom= (const int*)  d_in[3];
    const float* emb      = (const float*)d_in[4];
    const float* msg_w1   = (const float*)d_in[5];
    const float* msg_b1   = (const float*)d_in[6];
    const float* msg_w2   = (const float*)d_in[7];
    const float* msg_b2   = (const float*)d_in[8];
    const float* rbf_w    = (const float*)d_in[9];
    const float* rbf_b    = (const float*)d_in[10];
    const float* upd_U    = (const float*)d_in[11];
    const float* upd_V    = (const float*)d_in[12];
    const float* upd_w1   = (const float*)d_in[13];
    const float* upd_b1   = (const float*)d_in[14];
    const float* upd_w2   = (const float*)d_in[15];
    const float* upd_b2   = (const float*)d_in[16];
    const float* out_w1   = (const float*)d_in[17];
    const float* out_b1   = (const float*)d_in[18];
    const float* out_w2   = (const float*)d_in[19];
    const float* out_b2   = (const float*)d_in[20];
    float* out = (float*)d_out;

    float* ws   = (float*)d_ws;
    float* sA   = ws; ws += (size_t)NN*NF;
    float* sB   = ws; ws += (size_t)NN*NF;
    float* vA   = ws; ws += (size_t)NN*F3;
    float* vB   = ws; ws += (size_t)NN*F3;
    float* phiT = ws; ws += (size_t)F3*NN;
    float* vT   = ws; ws += (size_t)F3*NN;
    float* weG  = ws; ws += (size_t)NN*NA;
    float* dirG = ws; ws += (size_t)3*NN*NA;
    short* sp    = (short*)ws;
    short* tkF   = sp; sp += (size_t)NB*12*4*3*2*512;
    short* w1T_h = sp; sp += (size_t)NL*NF*NF;
    short* w1T_l = sp; sp += (size_t)NL*NF*NF;
    short* w2T_h = sp; sp += (size_t)NL*F3*NF;
    short* w2T_l = sp; sp += (size_t)NL*F3*NF;
    short* rbfT_h= sp; sp += (size_t)NL*F3*NK;
    short* rbfT_l= sp; sp += (size_t)NL*F3*NK;
    short* UT_h  = sp; sp += (size_t)NL*NF*NF;
    short* UT_l  = sp; sp += (size_t)NL*NF*NF;
    short* VT_h  = sp; sp += (size_t)NL*NF*NF;
    short* VT_l  = sp; sp += (size_t)NL*NF*NF;
    short* u1T_h = sp; sp += (size_t)NL*NF*2*NF;
    short* u1T_l = sp; sp += (size_t)NL*NF*2*NF;
    short* u2T_h = sp; sp += (size_t)NL*F3*NF;
    short* u2T_l = sp; sp += (size_t)NL*F3*NF;

    prep_kernel<<<dim3(NL*384, 7), 64, 0, stream>>>(msg_w1, msg_w2, rbf_w, upd_U, upd_V, upd_w1, upd_w2,
                                                    w1T_h, w1T_l, w2T_h, w2T_l, rbfT_h, rbfT_l,
                                                    UT_h, UT_l, VT_h, VT_l, u1T_h, u1T_l, u2T_h, u2T_l);
    geom_kernel<<<NB*12, 384, 0, stream>>>(pos, tkF, weG, dirG);
    zero_kernel<<<(F3*NN)/256, 256, 0, stream>>>(vT);
    init_phi_kernel<<<NN/16, 128, 0, stream>>>(emb, node_atom,
                                               w1T_h, w1T_l, msg_b1, w2T_h, w2T_l, msg_b2,
                                               sA, vA, phiT);

    float* sC = sA; float* vC = vA; float* sN = sB; float* vN = vB;
    for (int l = 0; l < NL; ++l) {
        message_kernel<<<NB*12, 512, 0, stream>>>(sC, vC, phiT, vT,
                                                  tkF, weG, dirG,
                                                  rbfT_h + (size_t)l*F3*NK,
                                                  rbf_b + (size_t)l*F3, sN, vN);
        int lp = (l + 1 < NL) ? (l + 1) : 0;
        update_phi_kernel<<<NN/16, 512, 0, stream>>>(
            UT_h + (size_t)l*NF*NF, UT_l + (size_t)l*NF*NF,
            VT_h + (size_t)l*NF*NF, VT_l + (size_t)l*NF*NF,
            u1T_h + (size_t)l*NF*2*NF, u1T_l + (size_t)l*NF*2*NF,
            upd_b1 + (size_t)l*NF,
            u2T_h + (size_t)l*F3*NF, u2T_l + (size_t)l*F3*NF,
            upd_b2 + (size_t)l*F3, sN, vN, vT,
            (l + 1 < NL) ? 1 : 0,
            w1T_h + (size_t)lp*NF*NF, w1T_l + (size_t)lp*NF*NF, msg_b1 + (size_t)lp*NF,
            w2T_h + (size_t)lp*F3*NF, w2T_l + (size_t)lp*F3*NF, msg_b2 + (size_t)lp*F3,
            phiT);
        float* tp;
        tp = sC; sC = sN; sN = tp;
        tp = vC; vC = vN; vN = tp;
    }
    zero_out_kernel<<<1, NB, 0, stream>>>(out);
    out_kernel<<<NN, NF, 0, stream>>>(sC, out_w1, out_b1, out_w2, out_b2, out);
}

// Round 9
// 746.041 us; speedup vs baseline: 2.0883x; 1.0075x over previous
//
#include <hip/hip_runtime.h>
#include <math.h>

#define NB 96
#define NA 48
#define NF 128
#define NK 64
#define NL 6
#define NN (NB*NA)     // 4608 nodes
#define F3 (3*NF)      // 384
#define CUTF 5.0f
#define GAMMA_F ((float)(1.0 / (0.006103515625 + 1e-9)))
#define PI_F 3.14159265358979323846f

typedef __attribute__((ext_vector_type(8))) short short8;
typedef __attribute__((ext_vector_type(4))) float floatx4;

__device__ __forceinline__ float silu_f(float x) { return x / (1.0f + expf(-x)); }

__device__ __forceinline__ short f2bf(float x) {
    unsigned u = __builtin_bit_cast(unsigned, x);
    unsigned r = (u + 0x7fffu + ((u >> 16) & 1u)) >> 16;   // RNE
    return (short)r;
}
__device__ __forceinline__ float bf2f(short h) {
    unsigned u = ((unsigned)(unsigned short)h) << 16;
    return __builtin_bit_cast(float, u);
}
__device__ __forceinline__ floatx4 mfma1(short8 a, short8 b, floatx4 c) {
    return __builtin_amdgcn_mfma_f32_16x16x32_bf16(a, b, c, 0, 0, 0);
}
__device__ __forceinline__ floatx4 mfma3(short8 ah, short8 al, short8 bh, short8 bl, floatx4 c) {
    c = __builtin_amdgcn_mfma_f32_16x16x32_bf16(ah, bh, c, 0, 0, 0);
    c = __builtin_amdgcn_mfma_f32_16x16x32_bf16(al, bh, c, 0, 0, 0);
    c = __builtin_amdgcn_mfma_f32_16x16x32_bf16(ah, bl, c, 0, 0, 0);
    return c;
}

// ---------------- fused prep: weights -> bf16 hi/lo in MFMA B-FRAGMENT ORDER ----------------
__global__ void prep_kernel(const float* __restrict__ msg_w1, const float* __restrict__ msg_w2,
                            const float* __restrict__ rbf_w, const float* __restrict__ upd_U,
                            const float* __restrict__ upd_V, const float* __restrict__ upd_w1,
                            const float* __restrict__ upd_w2,
                            short* w1T_h, short* w1T_l, short* w2T_h, short* w2T_l,
                            short* rbfT_h, short* rbfT_l, short* UT_h, short* UT_l,
                            short* VT_h, short* VT_l, short* u1T_h, short* u1T_l,
                            short* u2T_h, short* u2T_l) {
    int m = blockIdx.y;
    int l = blockIdx.x / 384;
    int n = blockIdx.x % 384;
    const float* src; short* dh; short* dl; int K, N;
    switch (m) {
      case 0: src = msg_w1; dh = w1T_h; dl = w1T_l; K = NF;   N = NF; break;
      case 1: src = msg_w2; dh = w2T_h; dl = w2T_l; K = NF;   N = F3; break;
      case 2: src = rbf_w;  dh = rbfT_h;dl = rbfT_l;K = NK;   N = F3; break;
      case 3: src = upd_U;  dh = UT_h;  dl = UT_l;  K = NF;   N = NF; break;
      case 4: src = upd_V;  dh = VT_h;  dl = VT_l;  K = NF;   N = NF; break;
      case 5: src = upd_w1; dh = u1T_h; dl = u1T_l; K = 2*NF; N = NF; break;
      default:src = upd_w2; dh = u2T_h; dl = u2T_l; K = NF;   N = F3; break;
    }
    if (n >= N) return;
    for (int k = threadIdx.x; k < K; k += 64) {
        float x = src[((size_t)l*K + k)*N + n];
        short h = f2bf(x);
        size_t off = (size_t)l*N*K
                   + (size_t)((((n>>4)*(K>>5) + (k>>5))*4 + ((k>>3)&3))*128 + (n&15)*8 + (k&7));
        dh[off] = h;
        dl[off] = f2bf(x - bf2f(h));
    }
}

// ---------------- geometry (once): tkF in MFMA A-FRAGMENT order + weG/dirG ----------------
__global__ void __launch_bounds__(384) geom_kernel(const float* __restrict__ pos,
                                                   short* __restrict__ tkF,
                                                   float* __restrict__ weG,
                                                   float* __restrict__ dirG) {
    int raw = blockIdx.x;                 // graph*12 + itile
    int graph = raw / 12, itile = raw % 12;
    int i0l = itile*4, jbase = graph*NA;
    int t = threadIdx.x;
    __shared__ float px[NA], py[NA], pz[NA];
    if (t < NA) {
        px[t] = pos[(jbase+t)*3 + 0];
        py[t] = pos[(jbase+t)*3 + 1];
        pz[t] = pos[(jbase+t)*3 + 2];
    }
    __syncthreads();
    int p = t >> 1, half = t & 1;         // 2 threads per (ii,j), 32 k-bins each
    int ii = p / NA, j = p % NA;
    int il = i0l + ii;
    float dx = px[il] - px[j], dy = py[il] - py[j], dz = pz[il] - pz[j];
    float d2 = dx*dx + dy*dy + dz*dz;
    float dd = sqrtf((j == il) ? 1.0f : d2);       // matches where(eye,1,d2)
    bool valid = (j != il) && (dd < CUTF);
    float we = valid ? 0.5f*(cosf(PI_F * dd / CUTF) + 1.0f) : 0.0f;
    int i = jbase + il;
    if (half == 0) {
        weG[(size_t)i*NA + j] = we;
        float inv = 1.0f / dd;
        dirG[0*(size_t)NN*NA + (size_t)i*NA + j] = dx*inv;
        dirG[1*(size_t)NN*NA + (size_t)i*NA + j] = dy*inv;
        dirG[2*(size_t)NN*NA + (size_t)i*NA + j] = dz*inv;
    }
    int mt = j >> 4, colj = j & 15;
    size_t base = ((((size_t)raw*4 + ii)*3 + mt)*2 + half)*512;
    #pragma unroll
    for (int c = 0; c < 4; ++c) {        // c = quad (k>>3 within 32-chunk)
        short8 h8;
        #pragma unroll
        for (int kk = 0; kk < 8; ++kk) {
            int k = half*32 + c*8 + kk;
            float cen = CUTF * (float)k / 63.0f;
            float df = dd - cen;
            h8[kk] = f2bf(__expf(-GAMMA_F * df * df) * we);
        }
        *(short8*)(tkF + base + (c*16 + colj)*8) = h8;
    }
}

__global__ void zero_kernel(float* __restrict__ p) {
    p[(size_t)blockIdx.x * blockDim.x + threadIdx.x] = 0.f;
}

// ---------------- init + phi(0) ----------------
__global__ void __launch_bounds__(128) init_phi_kernel(
        const float* __restrict__ emb, const int* __restrict__ node_atom,
        const short* __restrict__ w1T_h, const short* __restrict__ w1T_l,
        const float* __restrict__ b1,
        const short* __restrict__ w2T_h, const short* __restrict__ w2T_l,
        const float* __restrict__ b2,
        float* __restrict__ s, float* __restrict__ v, float* __restrict__ phiT) {
    __shared__ short sH[16*NF], sL[16*NF];
    __shared__ short hH[16*NF], hL[16*NF];
    int t = threadIdx.x;
    int w = t >> 6, lane = t & 63, quad = lane >> 4, col = lane & 15;
    int n0 = blockIdx.x * 16;
    for (int e = t; e < 16*NF; e += 128) {
        int n = e >> 7, f = e & 127;
        int a = node_atom[n0+n];
        float x = emb[(size_t)a*NF + f];
        s[(size_t)(n0+n)*NF + f] = x;
        short h = f2bf(x);
        int ad = n*NF + (((f >> 3) ^ (n & 7)) << 3) + (f & 7);
        sH[ad] = h; sL[ad] = f2bf(x - bf2f(h));
    }
    for (int e = t; e < 16*F3; e += 128) v[(size_t)n0*F3 + e] = 0.f;
    __syncthreads();
    #pragma unroll
    for (int nt = 0; nt < 4; ++nt) {
        int fh = w*64 + nt*16 + col;
        floatx4 acc = (floatx4){0.f,0.f,0.f,0.f};
        #pragma unroll
        for (int ks = 0; ks < 4; ++ks) {
            int ad = col*NF + (((ks*4 + quad) ^ (col & 7)) << 3);
            size_t off = (size_t)((((w*4 + nt)*4 + ks)*4 + quad)*128) + col*8;
            acc = mfma3(*(short8*)&sH[ad], *(short8*)&sL[ad],
                        *(const short8*)(w1T_h + off), *(const short8*)(w1T_l + off), acc);
        }
        float bias = b1[fh];
        #pragma unroll
        for (int r = 0; r < 4; ++r) {
            int n = quad*4 + r;
            float hv = silu_f(acc[r] + bias);
            short h = f2bf(hv);
            int ad = n*NF + (((fh >> 3) ^ (n & 7)) << 3) + (fh & 7);
            hH[ad] = h; hL[ad] = f2bf(hv - bf2f(h));
        }
    }
    __syncthreads();
    #pragma unroll
    for (int nt = 0; nt < 12; ++nt) {
        int tt = w*192 + nt*16 + col;
        floatx4 acc = (floatx4){0.f,0.f,0.f,0.f};
        #pragma unroll
        for (int ks = 0; ks < 4; ++ks) {
            int ad = col*NF + (((ks*4 + quad) ^ (col & 7)) << 3);
            size_t off = (size_t)((((w*12 + nt)*4 + ks)*4 + quad)*128) + col*8;
            acc = mfma3(*(short8*)&hH[ad], *(short8*)&hL[ad],
                        *(const short8*)(w2T_h + off), *(const short8*)(w2T_l + off), acc);
        }
        float bias = b2[tt];
        floatx4 o;
        #pragma unroll
        for (int r = 0; r < 4; ++r) o[r] = acc[r] + bias;
        *(floatx4*)(phiT + (size_t)tt*NN + n0 + quad*4) = o;
    }
}

// ---------------- message: block = (graph, 4-atom tile), 512 thr ----------------
// tk (24 KB, fragment-ordered) staged to LDS via 3 coalesced 16B loads/thread + 1 barrier;
// ia-loop reads A-fragments with conflict-free ds_read_b128. B-frags (hi-only) + j-side in regs.
__global__ void __launch_bounds__(512) message_kernel(
        const float* __restrict__ sIn, const float* __restrict__ vIn,
        const float* __restrict__ phiT, const float* __restrict__ vT,
        const short* __restrict__ tkF, const float* __restrict__ weG,
        const float* __restrict__ dirG,
        const short* __restrict__ rbfT_h,
        const float* __restrict__ rbf_b_l,
        float* __restrict__ sOut, float* __restrict__ vOut) {
    __shared__ short tkL[24*512];   // 24 KB
    int raw = blockIdx.x;
    int xcd = raw & 7, idx = raw >> 3;
    int graph = xcd + 8*(idx % 12);
    int itile = idx / 12;
    int i0l = itile*4, jbase = graph*NA;
    int t = threadIdx.x;
    int w = t >> 6, lane = t & 63, quad = lane >> 4, col = lane & 15;
    int f = w*16 + col;
    size_t tkbase = (size_t)(graph*12 + itile)*12288;
    // stage tk: contiguous copy, fully coalesced
    #pragma unroll
    for (int it = 0; it < 3; ++it) {
        int e = it*512 + t;
        *(short8*)&tkL[e*8] = *(const short8*)(tkF + tkbase + (size_t)e*8);
    }
    float rb0 = rbf_b_l[f], rb1 = rbf_b_l[NF+f], rb2 = rbf_b_l[2*NF+f];
    // hoisted B fragments (hi-only): [g][ks]
    short8 B[3][2];
    #pragma unroll
    for (int g = 0; g < 3; ++g)
        #pragma unroll
        for (int ks = 0; ks < 2; ++ks)
            B[g][ks] = *(const short8*)(rbfT_h + (size_t)((((g*8 + w)*2 + ks)*4 + quad)*128) + col*8);
    // hoisted j-side operands (atom-independent): float4 over j = mt*16+quad*4
    floatx4 ph0[3], ph1[3], ph2[3], vj0[3], vj1[3], vj2[3];
    #pragma unroll
    for (int mt = 0; mt < 3; ++mt) {
        int jq = jbase + mt*16 + quad*4;
        ph0[mt] = *(const floatx4*)(phiT + (size_t)f*NN + jq);
        ph1[mt] = *(const floatx4*)(phiT + (size_t)(NF+f)*NN + jq);
        ph2[mt] = *(const floatx4*)(phiT + (size_t)(2*NF+f)*NN + jq);
        vj0[mt] = *(const floatx4*)(vT + (size_t)(0*NF+f)*NN + jq);
        vj1[mt] = *(const floatx4*)(vT + (size_t)(1*NF+f)*NN + jq);
        vj2[mt] = *(const floatx4*)(vT + (size_t)(2*NF+f)*NN + jq);
    }
    __syncthreads();
    for (int ia = 0; ia < 4; ++ia) {
        floatx4 C[3][3];
        #pragma unroll
        for (int g = 0; g < 3; ++g)
            #pragma unroll
            for (int mt = 0; mt < 3; ++mt) C[g][mt] = (floatx4){0.f,0.f,0.f,0.f};
        #pragma unroll
        for (int mt = 0; mt < 3; ++mt) {
            #pragma unroll
            for (int ks = 0; ks < 2; ++ks) {
                short8 a = *(short8*)&tkL[(((ia*3 + mt)*2 + ks) << 9) + lane*8];
                #pragma unroll
                for (int g = 0; g < 3; ++g)
                    C[g][mt] = mfma1(a, B[g][ks], C[g][mt]);
            }
        }
        int i = jbase + i0l + ia;
        float accS = 0.f, av0 = 0.f, av1 = 0.f, av2 = 0.f;
        #pragma unroll
        for (int mt = 0; mt < 3; ++mt) {
            int jq = mt*16 + quad*4;
            floatx4 we4 = *(const floatx4*)(weG + (size_t)i*NA + jq);
            floatx4 d0 = *(const floatx4*)(dirG + 0*(size_t)NN*NA + (size_t)i*NA + jq);
            floatx4 d1 = *(const floatx4*)(dirG + 1*(size_t)NN*NA + (size_t)i*NA + jq);
            floatx4 d2 = *(const floatx4*)(dirG + 2*(size_t)NN*NA + (size_t)i*NA + jq);
            #pragma unroll
            for (int r = 0; r < 4; ++r) {
                float Wf0 = fmaf(rb0, we4[r], C[0][mt][r]);
                accS = fmaf(ph0[mt][r], Wf0, accS);
                float Wf1 = fmaf(rb1, we4[r], C[1][mt][r]);
                float x1 = ph1[mt][r] * Wf1;
                av0 = fmaf(x1, vj0[mt][r], av0);
                av1 = fmaf(x1, vj1[mt][r], av1);
                av2 = fmaf(x1, vj2[mt][r], av2);
                float Wf2 = fmaf(rb2, we4[r], C[2][mt][r]);
                float x2 = ph2[mt][r] * Wf2;
                av0 = fmaf(x2, d0[r], av0);
                av1 = fmaf(x2, d1[r], av1);
                av2 = fmaf(x2, d2[r], av2);
            }
        }
        accS += __shfl_xor(accS, 16, 64); accS += __shfl_xor(accS, 32, 64);
        av0 += __shfl_xor(av0, 16, 64);   av0 += __shfl_xor(av0, 32, 64);
        av1 += __shfl_xor(av1, 16, 64);   av1 += __shfl_xor(av1, 32, 64);
        av2 += __shfl_xor(av2, 16, 64);   av2 += __shfl_xor(av2, 32, 64);
        if (quad == 0) {
            sOut[(size_t)i*NF + f]        = sIn[(size_t)i*NF + f]        + accS;
            vOut[(size_t)i*F3 + f]        = vIn[(size_t)i*F3 + f]        + av0;
            vOut[(size_t)i*F3 + NF + f]   = vIn[(size_t)i*F3 + NF + f]   + av1;
            vOut[(size_t)i*F3 + 2*NF + f] = vIn[(size_t)i*F3 + 2*NF + f] + av2;
        }
    }
}

// ---------------- update (+ fused phi): 8 NODES/block (576 blocks), 512 thr = 8 waves ----------------
// MFMA M=16 tiles carry 8 real nodes (rows 8-15 garbage, row-isolated, writes guarded quad<2).
__global__ void __launch_bounds__(512) update_phi_kernel(
        const short* __restrict__ UT_h, const short* __restrict__ UT_l,
        const short* __restrict__ VT_h, const short* __restrict__ VT_l,
        const short* __restrict__ u1T_h, const short* __restrict__ u1T_l,
        const float* __restrict__ b1,
        const short* __restrict__ u2T_h, const short* __restrict__ u2T_l,
        const float* __restrict__ b2,
        float* __restrict__ s, float* __restrict__ v, float* __restrict__ vT,
        int doPhi,
        const short* __restrict__ pw1_h, const short* __restrict__ pw1_l,
        const float* __restrict__ pb1,
        const short* __restrict__ pw2_h, const short* __restrict__ pw2_l,
        const float* __restrict__ pb2,
        float* __restrict__ phiT) {
    __shared__ short A1h[48*NF], A1l[48*NF];    // v rows = c*16+n (n<8 used), swizzled
    __shared__ short A2h[16*256], A2l[16*256];  // [s ; Vn] (rows n<8 used); reused for s_new
    __shared__ short hH[16*NF], hL[16*NF];
    __shared__ float sF[8*132];
    int t = threadIdx.x;
    int w = t >> 6, lane = t & 63, quad = lane >> 4, col = lane & 15;
    int n0 = blockIdx.x * 8;
    int f = w*16 + col;                 // this wave's 16-feature tile
    for (int e = t; e < 8*F3; e += 512) {
        int n = e / F3, cf = e % F3;
        int c = cf >> 7, ff = cf & 127;
        float x = v[(size_t)(n0+n)*F3 + cf];
        int row = c*16 + n;
        short h = f2bf(x);
        int ad = row*NF + (((ff >> 3) ^ (row & 7)) << 3) + (ff & 7);
        A1h[ad] = h; A1l[ad] = f2bf(x - bf2f(h));
    }
    for (int e = t; e < 8*NF; e += 512) {
        int n = e >> 7, ff = e & 127;
        float x = s[(size_t)(n0+n)*NF + ff];
        sF[n*132 + ff] = x;
        short h = f2bf(x);
        int ad = n*256 + (((ff >> 3) ^ (n & 7)) << 3) + (ff & 7);
        A2h[ad] = h; A2l[ad] = f2bf(x - bf2f(h));
    }
    __syncthreads();
    floatx4 Uacc[3], Vacc[3];
    #pragma unroll
    for (int mt = 0; mt < 3; ++mt) { Uacc[mt] = (floatx4){0.f,0.f,0.f,0.f}; Vacc[mt] = (floatx4){0.f,0.f,0.f,0.f}; }
    #pragma unroll
    for (int ks = 0; ks < 4; ++ks) {
        size_t off = (size_t)(((w*4 + ks)*4 + quad)*128) + col*8;
        short8 BUh = *(const short8*)(UT_h + off), BUl = *(const short8*)(UT_l + off);
        short8 BVh = *(const short8*)(VT_h + off), BVl = *(const short8*)(VT_l + off);
        #pragma unroll
        for (int mt = 0; mt < 3; ++mt) {
            int row = mt*16 + col;
            int ad = row*NF + (((ks*4 + quad) ^ (row & 7)) << 3);
            short8 ah = *(short8*)&A1h[ad], al = *(short8*)&A1l[ad];
            Uacc[mt] = mfma3(ah, al, BUh, BUl, Uacc[mt]);
            Vacc[mt] = mfma3(ah, al, BVh, BVl, Vacc[mt]);
        }
    }
    if (quad < 2) {
        #pragma unroll
        for (int r = 0; r < 4; ++r) {
            int n = quad*4 + r;          // n < 8
            float v0 = Vacc[0][r], v1 = Vacc[1][r], v2 = Vacc[2][r];
            float vn = sqrtf(v0*v0 + v1*v1 + v2*v2 + 1e-8f);
            short h = f2bf(vn);
            int ad = n*256 + ((((128 + f) >> 3) ^ (n & 7)) << 3) + (f & 7);
            A2h[ad] = h; A2l[ad] = f2bf(vn - bf2f(h));
        }
    }
    __syncthreads();
    {
        floatx4 H = (floatx4){0.f,0.f,0.f,0.f};
        #pragma unroll
        for (int ks = 0; ks < 8; ++ks) {
            int ad = col*256 + (((ks*4 + quad) ^ (col & 7)) << 3);
            short8 ah = *(short8*)&A2h[ad], al = *(short8*)&A2l[ad];
            size_t off = (size_t)(((w*8 + ks)*4 + quad)*128) + col*8;
            H = mfma3(ah, al, *(const short8*)(u1T_h + off), *(const short8*)(u1T_l + off), H);
        }
        float bias = b1[f];
        if (quad < 2) {
            #pragma unroll
            for (int r = 0; r < 4; ++r) {
                int n = quad*4 + r;
                float hv = silu_f(H[r] + bias);
                short h = f2bf(hv);
                int ad = n*NF + (((f >> 3) ^ (n & 7)) << 3) + (f & 7);
                hH[ad] = h; hL[ad] = f2bf(hv - bf2f(h));
            }
        }
    }
    __syncthreads();
    floatx4 O[3];
    #pragma unroll
    for (int gg = 0; gg < 3; ++gg) O[gg] = (floatx4){0.f,0.f,0.f,0.f};
    #pragma unroll
    for (int ks = 0; ks < 4; ++ks) {
        int ad = col*NF + (((ks*4 + quad) ^ (col & 7)) << 3);
        short8 ah = *(short8*)&hH[ad], al = *(short8*)&hL[ad];
        #pragma unroll
        for (int gg = 0; gg < 3; ++gg) {
            size_t off = (size_t)((((gg*8 + w)*4 + ks)*4 + quad)*128) + col*8;
            O[gg] = mfma3(ah, al, *(const short8*)(u2T_h + off), *(const short8*)(u2T_l + off), O[gg]);
        }
    }
    __syncthreads();        // A2h/A2l free -> reuse for s_new (phi A operand)
    short* pH = A2h;
    short* pL = A2l;
    if (quad < 2) {
        float bavv = b2[f], basv = b2[NF + f], bass = b2[2*NF + f];
        #pragma unroll
        for (int r = 0; r < 4; ++r) {
            int n = quad*4 + r;          // n < 8
            float avv = O[0][r] + bavv;
            float asv = O[1][r] + basv;
            float ass = O[2][r] + bass;
            float dot = Uacc[0][r]*Vacc[0][r] + Uacc[1][r]*Vacc[1][r] + Uacc[2][r]*Vacc[2][r];
            float snew = sF[n*132 + f] + asv*dot + ass;
            s[(size_t)(n0+n)*NF + f] = snew;
            short sh = f2bf(snew);
            int adS = n*NF + (((f >> 3) ^ (n & 7)) << 3) + (f & 7);
            pH[adS] = sh; pL[adS] = f2bf(snew - bf2f(sh));
            #pragma unroll
            for (int c = 0; c < 3; ++c) {
                int row = c*16 + n;
                int ad = row*NF + (((f >> 3) ^ (row & 7)) << 3) + (f & 7);
                float vold = bf2f(A1h[ad]) + bf2f(A1l[ad]);
                float vnew = vold + avv*Uacc[c][r];
                v[(size_t)(n0+n)*F3 + c*NF + f] = vnew;
                vT[(size_t)(c*NF + f)*NN + n0 + n] = vnew;
            }
        }
    }
    if (!doPhi) return;
    __syncthreads();
    // phi GEMM1: wave w -> feature tile w (fh = w*16+col)
    {
        floatx4 acc = (floatx4){0.f,0.f,0.f,0.f};
        #pragma unroll
        for (int ks = 0; ks < 4; ++ks) {
            int ad = col*NF + (((ks*4 + quad) ^ (col & 7)) << 3);
            size_t off = (size_t)(((w*4 + ks)*4 + quad)*128) + col*8;
            acc = mfma3(*(short8*)&pH[ad], *(short8*)&pL[ad],
                        *(const short8*)(pw1_h + off), *(const short8*)(pw1_l + off), acc);
        }
        float bias = pb1[f];
        if (quad < 2) {
            #pragma unroll
            for (int r = 0; r < 4; ++r) {
                int n = quad*4 + r;
                float hv = silu_f(acc[r] + bias);
                short h = f2bf(hv);
                int ad = n*NF + (((f >> 3) ^ (n & 7)) << 3) + (f & 7);
                hH[ad] = h; hL[ad] = f2bf(hv - bf2f(h));
            }
        }
    }
    __syncthreads();
    // phi GEMM2: 8 waves x 3 tiles (tt = (w*3+nt)*16 + col)
    #pragma unroll
    for (int nt = 0; nt < 3; ++nt) {
        int tt = (w*3 + nt)*16 + col;
        floatx4 acc = (floatx4){0.f,0.f,0.f,0.f};
        #pragma unroll
        for (int ks = 0; ks < 4; ++ks) {
            int ad = col*NF + (((ks*4 + quad) ^ (col & 7)) << 3);
            size_t off = (size_t)((((w*3 + nt)*4 + ks)*4 + quad)*128) + col*8;
            acc = mfma3(*(short8*)&hH[ad], *(short8*)&hL[ad],
                        *(const short8*)(pw2_h + off), *(const short8*)(pw2_l + off), acc);
        }
        float bias = pb2[tt];
        if (quad < 2) {
            floatx4 o;
            #pragma unroll
            for (int r = 0; r < 4; ++r) o[r] = acc[r] + bias;
            *(floatx4*)(phiT + (size_t)tt*NN + n0 + quad*4) = o;
        }
    }
}

// ---------------- output head ----------------
__global__ void zero_out_kernel(float* __restrict__ out) {
    out[threadIdx.x] = 0.f;
}

__global__ void out_kernel(const float* __restrict__ s,
                           const float* __restrict__ w1, const float* __restrict__ b1,
                           const float* __restrict__ w2, const float* __restrict__ b2,
                           float* __restrict__ out) {
    int n = blockIdx.x;
    int f = threadIdx.x;
    __shared__ float sh[NF];
    __shared__ float r2[2];
    sh[f] = s[n*NF + f];
    __syncthreads();
    float acc = b1[f];
    for (int g = 0; g < NF; ++g) acc = fmaf(sh[g], w1[g*NF + f], acc);
    float p = silu_f(acc) * w2[f];
    #pragma unroll
    for (int off = 32; off > 0; off >>= 1) p += __shfl_down(p, off, 64);
    if ((f & 63) == 0) r2[f >> 6] = p;
    __syncthreads();
    if (f == 0) atomicAdd(&out[n / NA], r2[0] + r2[1] + b2[0]);
}

extern "C" void kernel_launch(void* const* d_in, const int* in_sizes, int n_in,
                              void* d_out, int out_size, void* d_ws, size_t ws_size,
                              hipStream_t stream) {
    (void)in_sizes; (void)n_in; (void)out_size; (void)ws_size;
    const float* pos      = (const float*)d_in[1];
    const int*   node_atom= (const int*)  d_in[3];
    const float* emb      = (const float*)d_in[4];
    const float* msg_w1   = (const float*)d_in[5];
    const float* msg_b1   = (const float*)d_in[6];
    const float* msg_w2   = (const float*)d_in[7];
    const float* msg_b2   = (const float*)d_in[8];
    const float* rbf_w    = (const float*)d_in[9];
    const float* rbf_b    = (const float*)d_in[10];
    const float* upd_U    = (const float*)d_in[11];
    const float* upd_V    = (const float*)d_in[12];
    const float* upd_w1   = (const float*)d_in[13];
    const float* upd_b1   = (const float*)d_in[14];
    const float* upd_w2   = (const float*)d_in[15];
    const float* upd_b2   = (const float*)d_in[16];
    const float* out_w1   = (const float*)d_in[17];
    const float* out_b1   = (const float*)d_in[18];
    const float* out_w2   = (const float*)d_in[19];
    const float* out_b2   = (const float*)d_in[20];
    float* out = (float*)d_out;

    float* ws   = (float*)d_ws;
    float* sA   = ws; ws += (size_t)NN*NF;
    float* sB   = ws; ws += (size_t)NN*NF;
    float* vA   = ws; ws += (size_t)NN*F3;
    float* vB   = ws; ws += (size_t)NN*F3;
    float* phiT = ws; ws += (size_t)F3*NN;
    float* vT   = ws; ws += (size_t)F3*NN;
    float* weG  = ws; ws += (size_t)NN*NA;
    float* dirG = ws; ws += (size_t)3*NN*NA;
    short* sp    = (short*)ws;
    short* tkF   = sp; sp += (size_t)NB*12*4*3*2*512;
    short* w1T_h = sp; sp += (size_t)NL*NF*NF;
    short* w1T_l = sp; sp += (size_t)NL*NF*NF;
    short* w2T_h = sp; sp += (size_t)NL*F3*NF;
    short* w2T_l = sp; sp += (size_t)NL*F3*NF;
    short* rbfT_h= sp; sp += (size_t)NL*F3*NK;
    short* rbfT_l= sp; sp += (size_t)NL*F3*NK;
    short* UT_h  = sp; sp += (size_t)NL*NF*NF;
    short* UT_l  = sp; sp += (size_t)NL*NF*NF;
    short* VT_h  = sp; sp += (size_t)NL*NF*NF;
    short* VT_l  = sp; sp += (size_t)NL*NF*NF;
    short* u1T_h = sp; sp += (size_t)NL*NF*2*NF;
    short* u1T_l = sp; sp += (size_t)NL*NF*2*NF;
    short* u2T_h = sp; sp += (size_t)NL*F3*NF;
    short* u2T_l = sp; sp += (size_t)NL*F3*NF;

    prep_kernel<<<dim3(NL*384, 7), 64, 0, stream>>>(msg_w1, msg_w2, rbf_w, upd_U, upd_V, upd_w1, upd_w2,
                                                    w1T_h, w1T_l, w2T_h, w2T_l, rbfT_h, rbfT_l,
                                                    UT_h, UT_l, VT_h, VT_l, u1T_h, u1T_l, u2T_h, u2T_l);
    geom_kernel<<<NB*12, 384, 0, stream>>>(pos, tkF, weG, dirG);
    zero_kernel<<<(F3*NN)/256, 256, 0, stream>>>(vT);
    init_phi_kernel<<<NN/16, 128, 0, stream>>>(emb, node_atom,
                                               w1T_h, w1T_l, msg_b1, w2T_h, w2T_l, msg_b2,
                                               sA, vA, phiT);

    float* sC = sA; float* vC = vA; float* sN = sB; float* vN = vB;
    for (int l = 0; l < NL; ++l) {
        message_kernel<<<NB*12, 512, 0, stream>>>(sC, vC, phiT, vT,
                                                  tkF, weG, dirG,
                                                  rbfT_h + (size_t)l*F3*NK,
                                                  rbf_b + (size_t)l*F3, sN, vN);
        int lp = (l + 1 < NL) ? (l + 1) : 0;
        update_phi_kernel<<<NN/8, 512, 0, stream>>>(
            UT_h + (size_t)l*NF*NF, UT_l + (size_t)l*NF*NF,
            VT_h + (size_t)l*NF*NF, VT_l + (size_t)l*NF*NF,
            u1T_h + (size_t)l*NF*2*NF, u1T_l + (size_t)l*NF*2*NF,
            upd_b1 + (size_t)l*NF,
            u2T_h + (size_t)l*F3*NF, u2T_l + (size_t)l*F3*NF,
            upd_b2 + (size_t)l*F3, sN, vN, vT,
            (l + 1 < NL) ? 1 : 0,
            w1T_h + (size_t)lp*NF*NF, w1T_l + (size_t)lp*NF*NF, msg_b1 + (size_t)lp*NF,
            w2T_h + (size_t)lp*F3*NF, w2T_l + (size_t)lp*F3*NF, msg_b2 + (size_t)lp*F3,
            phiT);
        float* tp;
        tp = sC; sC = sN; sN = tp;
        tp = vC; vC = vN; vN = tp;
    }
    zero_out_kernel<<<1, NB, 0, stream>>>(out);
    out_kernel<<<NN, NF, 0, stream>>>(sC, out_w1, out_b1, out_w2, out_b2, out);
}